// Round 5
// baseline (691.319 us; speedup 1.0000x reference)
//
#include <hip/hip_runtime.h>
#include <hip/hip_bf16.h>
#include <math.h>

#define NN 50000
#define NE 800000
#define NG 64
#define NEXP 8

typedef __attribute__((ext_vector_type(8))) short bf16x8;
typedef __attribute__((ext_vector_type(4))) float f32x4;
typedef unsigned short ushort_t;

__device__ __forceinline__ unsigned short f2bf(float f) {
  union { float f; unsigned u; } x; x.f = f;
  unsigned r = x.u + 0x7fff + ((x.u >> 16) & 1);  // RNE
  return (unsigned short)(r >> 16);
}
__device__ __forceinline__ float bf2f(unsigned short u) {
  union { unsigned u; float f; } x; x.u = ((unsigned)u) << 16; return x.f;
}

__device__ __forceinline__ void gld16(const void* g, void* l) {
  __builtin_amdgcn_global_load_lds(
      (const __attribute__((address_space(1))) unsigned int*)g,
      (__attribute__((address_space(3))) unsigned int*)l, 16, 0, 0);
}

// -------- encoder: h = relu(x@W_enc+b); hi/lo bf16 split (no fp32 copy) -----
__global__ __launch_bounds__(256) void k_encoder(
    const float* __restrict__ x, const float* __restrict__ W,
    const float* __restrict__ b, ushort_t* __restrict__ Xb,
    ushort_t* __restrict__ Xlo) {
  int i = blockIdx.x, n = threadIdx.x;
  float acc = b[n];
#pragma unroll
  for (int k = 0; k < 6; k++) acc = fmaf(x[i * 6 + k], W[k * 256 + n], acc);
  acc = fmaxf(acc, 0.f);
  unsigned short hb = f2bf(acc);
  Xb[(size_t)i * 512 + n] = hb;
  Xlo[(size_t)i * 256 + n] = f2bf(acc - bf2f(hb));  // bf16 residual (split-fp32)
}

// ---------------- per-graph node histogram ----------------
__global__ __launch_bounds__(256) void k_count_nodes(
    const int* __restrict__ batch, int* __restrict__ node_cnt) {
  __shared__ int bins[NG];
  int t = threadIdx.x;
  if (t < NG) bins[t] = 0;
  __syncthreads();
  for (int i = blockIdx.x * blockDim.x + t; i < NN; i += gridDim.x * blockDim.x)
    atomicAdd(&bins[batch[i]], 1);
  __syncthreads();
  if (t < NG) atomicAdd(&node_cnt[t], bins[t]);
}

// ---------------- per-graph edge histogram + in-degree ----------------
__global__ __launch_bounds__(256) void k_count_edges(
    const int* __restrict__ ei, const int* __restrict__ batch,
    int* __restrict__ edge_cnt, int* __restrict__ deg) {
  __shared__ int bins[NG];
  int t = threadIdx.x;
  if (t < NG) bins[t] = 0;
  __syncthreads();
  for (int e = blockIdx.x * blockDim.x + t; e < NE; e += gridDim.x * blockDim.x) {
    int s = ei[e];
    int d = ei[NE + e];
    atomicAdd(&bins[batch[s]], 1);
    atomicAdd(&deg[d], 1);
  }
  __syncthreads();
  if (t < NG) atomicAdd(&edge_cnt[t], bins[t]);
}

// ---------------- size features per node ----------------
__global__ __launch_bounds__(256) void k_sizefeat(
    const int* __restrict__ batch, const int* __restrict__ node_cnt,
    const int* __restrict__ edge_cnt, float* __restrict__ sf0,
    float* __restrict__ sf1) {
  int i = blockIdx.x * blockDim.x + threadIdx.x;
  if (i < NN) {
    int g = batch[i];
    sf0[i] = log1pf((float)node_cnt[g]);
    sf1[i] = log1pf((float)edge_cnt[g]);
  }
}

// ---------------- exclusive prefix scan of deg (single block) ----------------
__global__ __launch_bounds__(1024) void k_scan(
    const int* __restrict__ deg, int* __restrict__ offs, int* __restrict__ cursor) {
  __shared__ int wsums[16];
  int t = threadIdx.x, lane = t & 63, wid = t >> 6;
  int carry = 0;
  for (int base = 0; base < NN; base += 1024) {
    int i = base + t;
    int v = (i < NN) ? deg[i] : 0;
    int x = v;
#pragma unroll
    for (int d = 1; d < 64; d <<= 1) {
      int y = __shfl_up(x, d, 64);
      if (lane >= d) x += y;
    }
    if (lane == 63) wsums[wid] = x;
    __syncthreads();
    if (wid == 0) {
      int s = (lane < 16) ? wsums[lane] : 0;
#pragma unroll
      for (int d = 1; d < 16; d <<= 1) {
        int y = __shfl_up(s, d, 64);
        if (lane >= d) s += y;
      }
      if (lane < 16) wsums[lane] = s;
    }
    __syncthreads();
    int wpre = (wid > 0) ? wsums[wid - 1] : 0;
    int excl = carry + wpre + x - v;
    if (i < NN) { offs[i] = excl; cursor[i] = excl; }
    int btot = wsums[15];
    __syncthreads();
    carry += btot;
  }
  if (t == 0) offs[NN] = carry;
}

// ---------------- CSR fill: bucket edges by dst ----------------
__global__ __launch_bounds__(256) void k_fill_csr(
    const int* __restrict__ ei, int* __restrict__ cursor, int* __restrict__ edge_src) {
  int e = blockIdx.x * blockDim.x + threadIdx.x;
  if (e < NE) {
    int d = ei[NE + e];
    int pos = atomicAdd(&cursor[d], 1);
    edge_src[pos] = ei[e];
  }
}

// ------- A_h[i] = sum_{j in Nin(i)} h_bf[j] -> Xb[:, 256:512] (bf16) --------
// half-wave per edge, 16B loads, 8 gathers in flight
__global__ __launch_bounds__(256) void k_agg_h2(
    const int* __restrict__ offs, const int* __restrict__ edge_src,
    ushort_t* __restrict__ Xb) {
  int wid = threadIdx.x >> 6, lane = threadIdx.x & 63;
  int half = lane >> 5, cl = lane & 31;
  int i = blockIdx.x * 4 + wid;
  if (i >= NN) return;
  int e0 = offs[i], e1 = offs[i + 1];
  float acc[8] = {};
  int k = e0;
  for (; k + 8 <= e1; k += 8) {
    int s0 = edge_src[k + half];
    int s1 = edge_src[k + 2 + half];
    int s2 = edge_src[k + 4 + half];
    int s3 = edge_src[k + 6 + half];
    bf16x8 v0 = *(const bf16x8*)&Xb[(size_t)s0 * 512 + cl * 8];
    bf16x8 v1 = *(const bf16x8*)&Xb[(size_t)s1 * 512 + cl * 8];
    bf16x8 v2 = *(const bf16x8*)&Xb[(size_t)s2 * 512 + cl * 8];
    bf16x8 v3 = *(const bf16x8*)&Xb[(size_t)s3 * 512 + cl * 8];
#pragma unroll
    for (int j = 0; j < 8; j++) acc[j] += bf2f((unsigned short)v0[j]);
#pragma unroll
    for (int j = 0; j < 8; j++) acc[j] += bf2f((unsigned short)v1[j]);
#pragma unroll
    for (int j = 0; j < 8; j++) acc[j] += bf2f((unsigned short)v2[j]);
#pragma unroll
    for (int j = 0; j < 8; j++) acc[j] += bf2f((unsigned short)v3[j]);
  }
  for (; k + 2 <= e1; k += 2) {
    int s0 = edge_src[k + half];
    bf16x8 v0 = *(const bf16x8*)&Xb[(size_t)s0 * 512 + cl * 8];
#pragma unroll
    for (int j = 0; j < 8; j++) acc[j] += bf2f((unsigned short)v0[j]);
  }
  if (k < e1 && half == 0) {
    int s0 = edge_src[k];
    bf16x8 v0 = *(const bf16x8*)&Xb[(size_t)s0 * 512 + cl * 8];
#pragma unroll
    for (int j = 0; j < 8; j++) acc[j] += bf2f((unsigned short)v0[j]);
  }
#pragma unroll
  for (int j = 0; j < 8; j++) acc[j] += __shfl_xor(acc[j], 32, 64);
  if (half == 0) {
    bf16x8 o;
#pragma unroll
    for (int j = 0; j < 8; j++) o[j] = (short)f2bf(acc[j]);
    *(bf16x8*)(&Xb[(size_t)i * 512 + 256 + cl * 8]) = o;
  }
}

// ------ Wt[e][n][k] bf16, k in [0,512): k<256 from Ws[e][k][n], else Wn ------
__global__ __launch_bounds__(256) void k_prep_w(
    const float* __restrict__ Ws0, const float* __restrict__ Wn0,
    const float* __restrict__ Ws1, const float* __restrict__ Wn1,
    ushort_t* __restrict__ Wt1, ushort_t* __restrict__ Wt2) {
  __shared__ float tile[32][33];
  int z = blockIdx.z;
  int e = z & 7;
  const float* Ws = (z < 8) ? Ws0 : Ws1;
  const float* Wn = (z < 8) ? Wn0 : Wn1;
  ushort_t* Wt = (z < 8) ? Wt1 : Wt2;
  int kt = blockIdx.x;   // 16 k-tiles of 32 (over 512)
  int nt = blockIdx.y;   // 8 n-tiles of 32 (over 256)
  int tx = threadIdx.x & 31, ty = threadIdx.x >> 5;  // 32 x 8
  const float* src = (kt < 8) ? (Ws + e * 65536 + (kt * 32) * 256)
                              : (Wn + e * 65536 + ((kt - 8) * 32) * 256);
#pragma unroll
  for (int rr = 0; rr < 32; rr += 8) {
    int k = rr + ty;
    tile[k][tx] = src[k * 256 + nt * 32 + tx];
  }
  __syncthreads();
#pragma unroll
  for (int rr = 0; rr < 32; rr += 8) {
    int n = rr + ty;
    Wt[(size_t)e * 131072 + (nt * 32 + n) * 512 + kt * 32 + tx] = f2bf(tile[tx][n]);
  }
}

// ------ router weight split: Wr1t[n][k], k<256 hi(Wr1), k<512 lo(Wr1) -------
__global__ __launch_bounds__(256) void k_prep_wr1(
    const float* __restrict__ Wr1, ushort_t* __restrict__ Wr1t) {
  int k = blockIdx.x;       // 0..511
  int n = threadIdx.x;      // 0..255
  unsigned short v;
  if (k < 256) {
    v = f2bf(Wr1[k * 256 + n]);
  } else {
    float f = Wr1[(k - 256) * 256 + n];
    unsigned short h = f2bf(f);
    v = f2bf(f - bf2f(h));
  }
  Wr1t[(size_t)n * 512 + k] = v;
}

// ------ router GEMM, split-bf16, chunk-major LDS (bank-conflict-free) -------
// Phase hi (kt 0..7): acc += Xhi·Whi + Xhi·Wlo (A-tile shared, 2 B-tiles)
// Phase lo (kt 8..15): acc += Xlo·Whi
// LDS tile layout: [chunk q(4)][row(128)][16B] -> ds_read_b128 conflict-free.
// Epilogue: relu + fused partial logits -> Lpart[y][NN][8].
#define TIE_TAU 1e-4f
__global__ __launch_bounds__(256) void k_router_mfma(
    const ushort_t* __restrict__ Xb,    // [NN][512], cols 0..255 = hi(h)
    const ushort_t* __restrict__ Xlo,   // [NN][256] = lo(h)
    const ushort_t* __restrict__ Wr1t,  // [256][512] bf16 (n-major, hi|lo)
    const float* __restrict__ Wr1, const float* __restrict__ br1,
    const float* __restrict__ Wr2, const float* __restrict__ sf0,
    const float* __restrict__ sf1, float* __restrict__ Lpart) {
  __shared__ ushort_t As[2][4096];
  __shared__ ushort_t Bs1[2][4096];
  __shared__ ushort_t Bs2[2][4096];
  __shared__ float Lsm[128][NEXP];
  int t = threadIdx.x;
  int w = t >> 6, lane = t & 63;
  int m0 = blockIdx.x * 128;
  int n0 = blockIdx.y * 128;
  int wm = w >> 1, wn = w & 1;
  int q16 = lane >> 4, c15 = lane & 15;
  for (int z = t; z < 128 * NEXP; z += 256) ((float*)Lsm)[z] = 0.f;

  // chunk-major staging: lane's dest offset c*16B; ch=c>>7, r=c&127;
  // global source = row(r) + k0 + ch*8 elements
  auto STAGE = [&](int s, int kt) {
    int k0 = (kt & 7) * 32;
    bool hi = kt < 8;
#pragma unroll
    for (int i = 0; i < 2; i++) {
      int c = w * 128 + i * 64 + lane;
      int ch = c >> 7, r = c & 127;
      int gr = m0 + r; if (gr >= NN) gr = NN - 1;
      int dst = (w * 128 + i * 64) * 8;
      if (hi) {
        gld16(Xb + (size_t)gr * 512 + k0 + ch * 8, (void*)&As[s][dst]);
        gld16(Wr1t + (size_t)(n0 + r) * 512 + k0 + ch * 8, (void*)&Bs1[s][dst]);
        gld16(Wr1t + (size_t)(n0 + r) * 512 + 256 + k0 + ch * 8, (void*)&Bs2[s][dst]);
      } else {
        gld16(Xlo + (size_t)gr * 256 + k0 + ch * 8, (void*)&As[s][dst]);
        gld16(Wr1t + (size_t)(n0 + r) * 512 + k0 + ch * 8, (void*)&Bs1[s][dst]);
      }
    }
  };

  f32x4 acc[4][4] = {};
  STAGE(0, 0);
  __syncthreads();
  for (int kt = 0; kt < 16; kt++) {
    int cur = kt & 1;
    if (kt < 15) STAGE(cur ^ 1, kt + 1);
    bf16x8 a[4], b1[4];
#pragma unroll
    for (int i = 0; i < 4; i++) {
      int ra = wm * 64 + i * 16 + c15;
      a[i] = *(const bf16x8*)&As[cur][q16 * 1024 + ra * 8];
      int nb = wn * 64 + i * 16 + c15;
      b1[i] = *(const bf16x8*)&Bs1[cur][q16 * 1024 + nb * 8];
    }
#pragma unroll
    for (int i = 0; i < 4; i++)
#pragma unroll
      for (int j = 0; j < 4; j++)
        acc[i][j] = __builtin_amdgcn_mfma_f32_16x16x32_bf16(a[i], b1[j], acc[i][j], 0, 0, 0);
    if (kt < 8) {
      bf16x8 b2[4];
#pragma unroll
      for (int i = 0; i < 4; i++) {
        int nb = wn * 64 + i * 16 + c15;
        b2[i] = *(const bf16x8*)&Bs2[cur][q16 * 1024 + nb * 8];
      }
#pragma unroll
      for (int i = 0; i < 4; i++)
#pragma unroll
        for (int j = 0; j < 4; j++)
          acc[i][j] = __builtin_amdgcn_mfma_f32_16x16x32_bf16(a[i], b2[j], acc[i][j], 0, 0, 0);
    }
    __syncthreads();
  }

  // epilogue: R = relu(acc + br1 + sf·w67) in regs, partial logits -> Lsm
  float bb[4], w6[4], w7[4];
#pragma unroll
  for (int j = 0; j < 4; j++) {
    int col = n0 + wn * 64 + j * 16 + c15;
    bb[j] = br1[col];
    w6[j] = Wr1[65536 + col];
    w7[j] = Wr1[65792 + col];
  }
#pragma unroll
  for (int i = 0; i < 4; i++)
#pragma unroll
    for (int v = 0; v < 4; v++) {
      int row = m0 + wm * 64 + i * 16 + q16 * 4 + v;
      float s0v = (row < NN) ? sf0[row] : 0.f;
      float s1v = (row < NN) ? sf1[row] : 0.f;
#pragma unroll
      for (int j = 0; j < 4; j++)
        acc[i][j][v] = fmaxf(acc[i][j][v] + bb[j] + s0v * w6[j] + s1v * w7[j], 0.f);
    }
#pragma unroll
  for (int e = 0; e < NEXP; e++) {
    float wr2j[4];
#pragma unroll
    for (int j = 0; j < 4; j++)
      wr2j[j] = Wr2[(n0 + wn * 64 + j * 16 + c15) * 8 + e];
    float pe[4][4];
#pragma unroll
    for (int i = 0; i < 4; i++)
#pragma unroll
      for (int v = 0; v < 4; v++) {
        float s = acc[i][0][v] * wr2j[0];
        s = fmaf(acc[i][1][v], wr2j[1], s);
        s = fmaf(acc[i][2][v], wr2j[2], s);
        s = fmaf(acc[i][3][v], wr2j[3], s);
        pe[i][v] = s;
      }
#pragma unroll
    for (int d = 1; d < 16; d <<= 1)
#pragma unroll
      for (int i = 0; i < 4; i++)
#pragma unroll
        for (int v = 0; v < 4; v++)
          pe[i][v] += __shfl_xor(pe[i][v], d, 64);
    if (c15 == 0) {
#pragma unroll
      for (int i = 0; i < 4; i++)
#pragma unroll
        for (int v = 0; v < 4; v++)
          atomicAdd(&Lsm[wm * 64 + i * 16 + q16 * 4 + v][e], pe[i][v]);
    }
  }
  __syncthreads();
  for (int z = t; z < 128 * NEXP; z += 256) {
    int lr = z >> 3, e = z & 7;
    int row = m0 + lr;
    if (row < NN)
      Lpart[(size_t)blockIdx.y * (NN * 8) + (size_t)row * 8 + e] = Lsm[lr][e];
  }
}

// ------ argmax over fused partial logits; near-ties queued for fixup --------
__global__ __launch_bounds__(256) void k_argmax(
    const float* __restrict__ Lpart, const float* __restrict__ br2,
    int* __restrict__ idx, int* __restrict__ nfix, int* __restrict__ fixlist) {
  int i = blockIdx.x * 256 + threadIdx.x;
  if (i >= NN) return;
  float best = -1e30f, second = -1e30f; int bi = 0;
#pragma unroll
  for (int e = 0; e < NEXP; e++) {
    float v = br2[e] + Lpart[(size_t)i * 8 + e]
              + Lpart[(size_t)(NN * 8) + (size_t)i * 8 + e];
    if (v > best) { second = best; best = v; bi = e; }  // strict >: first-wins
    else if (v > second) second = v;
  }
  idx[i] = bi;
  if (best - second < TIE_TAU) {
    int p = atomicAdd(nfix, 1);
    fixlist[p] = i;
  }
}

// ------ fp32 re-route for near-tie nodes (recomputes h from x) --------------
__global__ __launch_bounds__(256) void k_fixup(
    const float* __restrict__ x, const float* __restrict__ W_enc,
    const float* __restrict__ b_enc, const float* __restrict__ Wr1,
    const float* __restrict__ br1, const float* __restrict__ Wr2,
    const float* __restrict__ br2, const float* __restrict__ sf0,
    const float* __restrict__ sf1, const int* __restrict__ fixlist,
    const int* __restrict__ nfix, int* __restrict__ idx) {
  __shared__ float hsh[256];
  __shared__ float lred[4][NEXP];
  int n = *nfix;
  int t = threadIdx.x, wid = t >> 6, lane = t & 63;
  for (int qq = blockIdx.x; qq < n; qq += gridDim.x) {
    int node = fixlist[qq];
    float hv = b_enc[t];
#pragma unroll
    for (int k = 0; k < 6; k++)
      hv = fmaf(x[node * 6 + k], W_enc[k * 256 + t], hv);
    hsh[t] = fmaxf(hv, 0.f);
    __syncthreads();
    float acc = br1[t] + sf0[node] * Wr1[65536 + t] + sf1[node] * Wr1[65792 + t];
    for (int k = 0; k < 256; k++)
      acc = fmaf(hsh[k], Wr1[k * 256 + t], acc);
    float r = fmaxf(acc, 0.f);
    float le[NEXP];
#pragma unroll
    for (int e = 0; e < NEXP; e++) le[e] = r * Wr2[t * 8 + e];
#pragma unroll
    for (int d = 32; d > 0; d >>= 1)
#pragma unroll
      for (int e = 0; e < NEXP; e++) le[e] += __shfl_xor(le[e], d, 64);
    if (lane == 0) {
#pragma unroll
      for (int e = 0; e < NEXP; e++) lred[wid][e] = le[e];
    }
    __syncthreads();
    if (t == 0) {
      float best = -1e30f; int bi = 0;
      for (int e = 0; e < NEXP; e++) {
        float v = lred[0][e] + lred[1][e] + lred[2][e] + lred[3][e] + br2[e];
        if (v > best) { best = v; bi = e; }
      }
      idx[node] = bi;
    }
    __syncthreads();
  }
}

// ------ expert histogram ------
__global__ __launch_bounds__(256) void k_ecnt(
    const int* __restrict__ idx, int* __restrict__ ecnt) {
  __shared__ int bins[NEXP];
  int t = threadIdx.x;
  if (t < NEXP) bins[t] = 0;
  __syncthreads();
  for (int i = blockIdx.x * 256 + t; i < NN; i += gridDim.x * 256)
    atomicAdd(&bins[idx[i]], 1);
  __syncthreads();
  if (t < NEXP) atomicAdd(&ecnt[t], bins[t]);
}

// ------ source mask: mask[j] bit e set iff z_e[j] is needed ------
__global__ __launch_bounds__(256) void k_srcmask(
    const int* __restrict__ ei, const int* __restrict__ idx,
    unsigned int* __restrict__ mask) {
  int k = blockIdx.x * 256 + threadIdx.x;
  if (k < NE) {
    int s = ei[k], d = ei[NE + k];
    atomicOr(&mask[s], 1u << idx[d]);
  }
  if (k < NN) atomicOr(&mask[k], 1u << idx[k]);  // self bit
}

// ------ per-expert source-list sizes ------
__global__ __launch_bounds__(256) void k_scount(
    const unsigned int* __restrict__ mask, int* __restrict__ scnt) {
  __shared__ int bins[NEXP];
  int t = threadIdx.x;
  if (t < NEXP) bins[t] = 0;
  __syncthreads();
  for (int i = blockIdx.x * 256 + t; i < NN; i += gridDim.x * 256) {
    unsigned m = mask[i];
    while (m) { int b = __ffs(m) - 1; atomicAdd(&bins[b], 1); m &= m - 1; }
  }
  __syncthreads();
  if (t < NEXP) atomicAdd(&scnt[t], bins[t]);
}

// boff/bcur + tile starts + source-list offsets
__global__ void k_bucket_offs(const int* __restrict__ ecnt,
                              const int* __restrict__ scnt,
                              int* __restrict__ boff, int* __restrict__ bcur,
                              int* __restrict__ tstart,
                              int* __restrict__ soff, int* __restrict__ scur) {
  if (threadIdx.x == 0) {
    int s = 0, ts = 0, s2 = 0;
    for (int e = 0; e < NEXP; e++) {
      boff[e] = s; bcur[e] = s;
      tstart[e] = ts;
      ts += (ecnt[e] + 127) / 128;
      s += ecnt[e];
      soff[e] = s2; scur[e] = s2;
      s2 += scnt[e];
    }
    boff[NEXP] = s;
    tstart[NEXP] = ts;
    soff[NEXP] = s2;
  }
}

// ---- block-aggregated bucket fill ----
#define BF_BLOCKS 64
__global__ __launch_bounds__(256) void k_bucket_fill2(
    const int* __restrict__ idx, int* __restrict__ bcur, int* __restrict__ nlist) {
  __shared__ int lcnt[NEXP];
  __shared__ int lbase[NEXP];
  int t = threadIdx.x;
  int chunk = (NN + BF_BLOCKS - 1) / BF_BLOCKS;
  int lo = blockIdx.x * chunk;
  int hi = lo + chunk; if (hi > NN) hi = NN;
  if (t < NEXP) lcnt[t] = 0;
  __syncthreads();
  for (int i = lo + t; i < hi; i += 256) atomicAdd(&lcnt[idx[i]], 1);
  __syncthreads();
  if (t < NEXP) lbase[t] = atomicAdd(&bcur[t], lcnt[t]);
  __syncthreads();
  if (t < NEXP) lcnt[t] = 0;
  __syncthreads();
  for (int i = lo + t; i < hi; i += 256) {
    int e = idx[i];
    int p = atomicAdd(&lcnt[e], 1);
    nlist[lbase[e] + p] = i;
  }
}

// ---- compact per-expert source lists from mask ----
__global__ __launch_bounds__(256) void k_scompact(
    const unsigned int* __restrict__ mask, int* __restrict__ scur,
    int* __restrict__ slist) {
  __shared__ int lcnt[NEXP];
  __shared__ int lbase[NEXP];
  int t = threadIdx.x;
  int chunk = (NN + BF_BLOCKS - 1) / BF_BLOCKS;
  int lo = blockIdx.x * chunk;
  int hi = lo + chunk; if (hi > NN) hi = NN;
  if (t < NEXP) lcnt[t] = 0;
  __syncthreads();
  for (int i = lo + t; i < hi; i += 256) {
    unsigned m = mask[i];
    while (m) { int b = __ffs(m) - 1; atomicAdd(&lcnt[b], 1); m &= m - 1; }
  }
  __syncthreads();
  if (t < NEXP) lbase[t] = atomicAdd(&scur[t], lcnt[t]);
  __syncthreads();
  if (t < NEXP) lcnt[t] = 0;
  __syncthreads();
  for (int i = lo + t; i < hi; i += 256) {
    unsigned m = mask[i];
    while (m) {
      int b = __ffs(m) - 1;
      int p = atomicAdd(&lcnt[b], 1);
      slist[lbase[b] + p] = i;
      m &= m - 1;
    }
  }
}

// ------- layer1 rows-gather MFMA, dbuf + chunk-major LDS (conflict-free) ----
__global__ __launch_bounds__(256) void k_layer1_rows(
    const ushort_t* __restrict__ Abf,  // Xb [NN][512] bf16
    const ushort_t* __restrict__ Wt,   // [8][256][512] bf16 (n-major)
    const float* __restrict__ b0, const int* __restrict__ idx,
    const int* __restrict__ slist, const int* __restrict__ soff, int e,
    ushort_t* __restrict__ Zb, ushort_t* __restrict__ A2) {
  int base = soff[e];
  int cnt = soff[e + 1] - base;
  int m0 = blockIdx.x * 128;
  if (m0 >= cnt) return;
  __shared__ ushort_t As[2][4096];
  __shared__ ushort_t Bs[2][4096];
  __shared__ int rows[128];
  __shared__ int sidx[128];
  int t = threadIdx.x;
  if (t < 128) {
    int r = (m0 + t < cnt) ? slist[base + m0 + t] : -1;
    rows[t] = r;
    sidx[t] = (r >= 0) ? idx[r] : -1;
  }
  __syncthreads();
  int w = t >> 6, lane = t & 63;
  int n0 = blockIdx.y * 128;
  int wm = w >> 1, wn = w & 1;
  int q16 = lane >> 4, c15 = lane & 15;
  const ushort_t* Wb = Wt + (size_t)e * 131072;

  auto STAGE = [&](int s, int kt) {
    int k0 = kt * 32;
#pragma unroll
    for (int i = 0; i < 2; i++) {
      int c = w * 128 + i * 64 + lane;
      int ch = c >> 7, r = c & 127;
      int nd = rows[r]; if (nd < 0) nd = 0;
      int dst = (w * 128 + i * 64) * 8;
      gld16(Abf + (size_t)nd * 512 + k0 + ch * 8, (void*)&As[s][dst]);
      gld16(Wb + (size_t)(n0 + r) * 512 + k0 + ch * 8, (void*)&Bs[s][dst]);
    }
  };

  f32x4 acc[4][4] = {};
  STAGE(0, 0);
  __syncthreads();
  for (int kt = 0; kt < 16; kt++) {
    int cur = kt & 1;
    if (kt < 15) STAGE(cur ^ 1, kt + 1);
    bf16x8 a[4], b[4];
#pragma unroll
    for (int i = 0; i < 4; i++) {
      int ra = wm * 64 + i * 16 + c15;
      a[i] = *(const bf16x8*)&As[cur][q16 * 1024 + ra * 8];
      int nb = wn * 64 + i * 16 + c15;
      b[i] = *(const bf16x8*)&Bs[cur][q16 * 1024 + nb * 8];
    }
#pragma unroll
    for (int i = 0; i < 4; i++)
#pragma unroll
      for (int j = 0; j < 4; j++)
        acc[i][j] = __builtin_amdgcn_mfma_f32_16x16x32_bf16(a[i], b[j], acc[i][j], 0, 0, 0);
    __syncthreads();
  }
  int q = lane >> 4;
#pragma unroll
  for (int i = 0; i < 4; i++) {
#pragma unroll
    for (int j = 0; j < 4; j++) {
      int col = n0 + wn * 64 + j * 16 + c15;
      float bias = b0[e * 256 + col];
#pragma unroll
      for (int v = 0; v < 4; v++) {
        int lrow = wm * 64 + i * 16 + q * 4 + v;
        int node = rows[lrow];
        if (node >= 0) {
          unsigned short zb = f2bf(fmaxf(acc[i][j][v] + bias, 0.f));
          Zb[(size_t)node * 256 + col] = zb;
          if (sidx[lrow] == e) A2[(size_t)node * 512 + col] = zb;
        }
      }
    }
  }
}

// ---- agg_z bucket e (persistent grid): A2[i,256:512] = sum Zb[Nin(i)] ------
__global__ __launch_bounds__(256) void k_agg_z2(
    const ushort_t* __restrict__ Zb, const int* __restrict__ offs,
    const int* __restrict__ edge_src, const int* __restrict__ nlist,
    const int* __restrict__ boff, int e, ushort_t* __restrict__ A2) {
  int wid = threadIdx.x >> 6, lane = threadIdx.x & 63;
  int half = lane >> 5, cl = lane & 31;
  int base = boff[e];
  int cnt = boff[e + 1] - base;
  for (int b = blockIdx.x * 4 + wid; b < cnt; b += gridDim.x * 4) {
    int i = nlist[base + b];
    int e0 = offs[i], e1 = offs[i + 1];
    float acc[8] = {};
    int k = e0;
    for (; k + 8 <= e1; k += 8) {
      int s0 = edge_src[k + half];
      int s1 = edge_src[k + 2 + half];
      int s2 = edge_src[k + 4 + half];
      int s3 = edge_src[k + 6 + half];
      bf16x8 v0 = *(const bf16x8*)&Zb[(size_t)s0 * 256 + cl * 8];
      bf16x8 v1 = *(const bf16x8*)&Zb[(size_t)s1 * 256 + cl * 8];
      bf16x8 v2 = *(const bf16x8*)&Zb[(size_t)s2 * 256 + cl * 8];
      bf16x8 v3 = *(const bf16x8*)&Zb[(size_t)s3 * 256 + cl * 8];
#pragma unroll
      for (int j = 0; j < 8; j++) acc[j] += bf2f((unsigned short)v0[j]);
#pragma unroll
      for (int j = 0; j < 8; j++) acc[j] += bf2f((unsigned short)v1[j]);
#pragma unroll
      for (int j = 0; j < 8; j++) acc[j] += bf2f((unsigned short)v2[j]);
#pragma unroll
      for (int j = 0; j < 8; j++) acc[j] += bf2f((unsigned short)v3[j]);
    }
    for (; k + 2 <= e1; k += 2) {
      int s0 = edge_src[k + half];
      bf16x8 v0 = *(const bf16x8*)&Zb[(size_t)s0 * 256 + cl * 8];
#pragma unroll
      for (int j = 0; j < 8; j++) acc[j] += bf2f((unsigned short)v0[j]);
    }
    if (k < e1 && half == 0) {
      int s0 = edge_src[k];
      bf16x8 v0 = *(const bf16x8*)&Zb[(size_t)s0 * 256 + cl * 8];
#pragma unroll
      for (int j = 0; j < 8; j++) acc[j] += bf2f((unsigned short)v0[j]);
    }
#pragma unroll
    for (int j = 0; j < 8; j++) acc[j] += __shfl_xor(acc[j], 32, 64);
    if (half == 0) {
      bf16x8 o;
#pragma unroll
      for (int j = 0; j < 8; j++) o[j] = (short)f2bf(acc[j]);
      *(bf16x8*)(&A2[(size_t)i * 512 + 256 + cl * 8]) = o;
    }
  }
}

// ------- fused layer2 MFMA, dbuf + chunk-major LDS (conflict-free) ----------
#define MAXT2 (391 + NEXP)
__global__ __launch_bounds__(256) void k_layer2_mfma(
    const ushort_t* __restrict__ A2,   // [NN][512] bf16
    const ushort_t* __restrict__ Wt,   // [8][256][512] bf16 (n-major)
    const float* __restrict__ b1, const int* __restrict__ nlist,
    const int* __restrict__ boff, const int* __restrict__ tstart,
    float* __restrict__ outp) {
  __shared__ ushort_t As[2][4096];
  __shared__ ushort_t Bs[2][4096];
  __shared__ int rows[128];
  int t = threadIdx.x;
  int tx = blockIdx.x;
  int e = -1;
#pragma unroll
  for (int q = 0; q < NEXP; q++)
    if (tx >= tstart[q] && tx < tstart[q + 1]) e = q;
  if (e < 0) return;
  int tile = tx - tstart[e];
  int base = boff[e];
  int cnt = boff[e + 1] - base;
  int m0 = tile * 128;
  if (t < 128) rows[t] = (m0 + t < cnt) ? nlist[base + m0 + t] : -1;
  __syncthreads();
  int w = t >> 6, lane = t & 63;
  int n0 = blockIdx.y * 128;
  int wm = w >> 1, wn = w & 1;
  int q16 = lane >> 4, c15 = lane & 15;
  const ushort_t* Wb = Wt + (size_t)e * 131072;

  auto STAGE = [&](int s, int kt) {
    int k0 = kt * 32;
#pragma unroll
    for (int i = 0; i < 2; i++) {
      int c = w * 128 + i * 64 + lane;
      int ch = c >> 7, r = c & 127;
      int nd = rows[r]; if (nd < 0) nd = 0;
      int dst = (w * 128 + i * 64) * 8;
      gld16(A2 + (size_t)nd * 512 + k0 + ch * 8, (void*)&As[s][dst]);
      gld16(Wb + (size_t)(n0 + r) * 512 + k0 + ch * 8, (void*)&Bs[s][dst]);
    }
  };

  f32x4 acc[4][4] = {};
  STAGE(0, 0);
  __syncthreads();
  for (int kt = 0; kt < 16; kt++) {
    int cur = kt & 1;
    if (kt < 15) STAGE(cur ^ 1, kt + 1);
    bf16x8 a[4], b[4];
#pragma unroll
    for (int i = 0; i < 4; i++) {
      int ra = wm * 64 + i * 16 + c15;
      a[i] = *(const bf16x8*)&As[cur][q16 * 1024 + ra * 8];
      int nb = wn * 64 + i * 16 + c15;
      b[i] = *(const bf16x8*)&Bs[cur][q16 * 1024 + nb * 8];
    }
#pragma unroll
    for (int i = 0; i < 4; i++)
#pragma unroll
      for (int j = 0; j < 4; j++)
        acc[i][j] = __builtin_amdgcn_mfma_f32_16x16x32_bf16(a[i], b[j], acc[i][j], 0, 0, 0);
    __syncthreads();
  }
  int q = lane >> 4;
#pragma unroll
  for (int i = 0; i < 4; i++) {
#pragma unroll
    for (int j = 0; j < 4; j++) {
      int col = n0 + wn * 64 + j * 16 + c15;
      float bias = b1[e * 256 + col];
#pragma unroll
      for (int v = 0; v < 4; v++) {
        int lrow = wm * 64 + i * 16 + q * 4 + v;
        int node = rows[lrow];
        if (node >= 0) outp[(size_t)node * 256 + col] = acc[i][j][v] + bias;
      }
    }
  }
}

static inline char* wsalloc(char*& p, size_t bytes) {
  char* r = p;
  p += (bytes + 255) & ~(size_t)255;
  return r;
}

extern "C" void kernel_launch(void* const* d_in, const int* in_sizes, int n_in,
                              void* d_out, int out_size, void* d_ws, size_t ws_size,
                              hipStream_t stream) {
  const float* x     = (const float*)d_in[0];
  const int*   ei    = (const int*)d_in[1];
  const int*   batch = (const int*)d_in[2];
  const float* W_enc = (const float*)d_in[3];
  const float* b_enc = (const float*)d_in[4];
  const float* Wr1   = (const float*)d_in[5];
  const float* br1   = (const float*)d_in[6];
  const float* Wr2   = (const float*)d_in[7];
  const float* br2   = (const float*)d_in[8];
  const float* Ws0   = (const float*)d_in[9];
  const float* Wn0   = (const float*)d_in[10];
  const float* b0    = (const float*)d_in[11];
  const float* Ws1   = (const float*)d_in[12];
  const float* Wn1   = (const float*)d_in[13];
  const float* b1    = (const float*)d_in[14];
  float* outp = (float*)d_out;

  char* p = (char*)d_ws;
  ushort_t* Xb   = (ushort_t*)wsalloc(p, (size_t)NN * 512 * 2);  // [h | A_h] bf16
  ushort_t* Zb   = (ushort_t*)wsalloc(p, (size_t)NN * 256 * 2);  // z_e bf16
  ushort_t* A2   = (ushort_t*)wsalloc(p, (size_t)NN * 512 * 2);  // [z_self | agg] bf16
  ushort_t* Xlo  = Zb;              // alias: Xlo dies before Zb born (layer1)
  float*    Lpart= (float*)wsalloc(p, (size_t)2 * NN * 8 * 4);   // fused logit partials
  ushort_t* Wt1  = (ushort_t*)wsalloc(p, (size_t)NEXP * 256 * 512 * 2);
  ushort_t* Wt2  = (ushort_t*)wsalloc(p, (size_t)NEXP * 256 * 512 * 2);
  ushort_t* Wr1t = (ushort_t*)wsalloc(p, (size_t)256 * 512 * 2);
  int* edge_src  = (int*)wsalloc(p, (size_t)NE * 4);
  int* offs      = (int*)wsalloc(p, (size_t)(NN + 1) * 4);
  int* cursor    = (int*)wsalloc(p, (size_t)NN * 4);
  int* deg       = (int*)wsalloc(p, (size_t)NN * 4);
  int* idxb      = (int*)wsalloc(p, (size_t)NN * 4);
  float* sf0     = (float*)wsalloc(p, (size_t)NN * 4);
  float* sf1     = (float*)wsalloc(p, (size_t)NN * 4);
  int* nlist     = (int*)wsalloc(p, (size_t)NN * 4);
  int* fixlist   = (int*)wsalloc(p, (size_t)NN * 4);
  unsigned int* maskb = (unsigned int*)wsalloc(p, (size_t)NN * 4);
  int* slist     = (int*)wsalloc(p, (size_t)NN * NEXP * 4);
  int* smallb    = (int*)wsalloc(p, 256 * 4);
  int* node_cnt = smallb;        // 64
  int* edge_cnt = smallb + 64;   // 64
  int* ecnt     = smallb + 128;  // 8
  int* boff     = smallb + 136;  // 9
  int* bcur     = smallb + 152;  // 8
  int* tstart   = smallb + 160;  // 9
  int* nfix     = smallb + 192;  // 1
  int* scnt     = smallb + 200;  // 8
  int* soff     = smallb + 208;  // 9
  int* scur     = smallb + 224;  // 8

  hipMemsetAsync(deg, 0, (size_t)NN * 4, stream);
  hipMemsetAsync(smallb, 0, 256 * 4, stream);
  hipMemsetAsync(maskb, 0, (size_t)NN * 4, stream);

  k_encoder<<<NN, 256, 0, stream>>>(x, W_enc, b_enc, Xb, Xlo);
  k_count_nodes<<<64, 256, 0, stream>>>(batch, node_cnt);
  k_count_edges<<<128, 256, 0, stream>>>(ei, batch, edge_cnt, deg);
  k_sizefeat<<<(NN + 255) / 256, 256, 0, stream>>>(batch, node_cnt, edge_cnt, sf0, sf1);
  k_scan<<<1, 1024, 0, stream>>>(deg, offs, cursor);
  k_fill_csr<<<(NE + 255) / 256, 256, 0, stream>>>(ei, cursor, edge_src);
  k_agg_h2<<<(NN + 3) / 4, 256, 0, stream>>>(offs, edge_src, Xb);
  k_prep_w<<<dim3(16, 8, 16), 256, 0, stream>>>(Ws0, Wn0, Ws1, Wn1, Wt1, Wt2);
  k_prep_wr1<<<512, 256, 0, stream>>>(Wr1, Wr1t);
  k_router_mfma<<<dim3((NN + 127) / 128, 2), 256, 0, stream>>>(
      Xb, Xlo, Wr1t, Wr1, br1, Wr2, sf0, sf1, Lpart);
  k_argmax<<<(NN + 255) / 256, 256, 0, stream>>>(Lpart, br2, idxb, nfix, fixlist);
  k_fixup<<<256, 256, 0, stream>>>(x, W_enc, b_enc, Wr1, br1, Wr2, br2,
                                   sf0, sf1, fixlist, nfix, idxb);
  k_srcmask<<<(NE + 255) / 256, 256, 0, stream>>>(ei, idxb, maskb);
  k_ecnt<<<64, 256, 0, stream>>>(idxb, ecnt);
  k_scount<<<64, 256, 0, stream>>>(maskb, scnt);
  k_bucket_offs<<<1, 64, 0, stream>>>(ecnt, scnt, boff, bcur, tstart, soff, scur);
  k_bucket_fill2<<<BF_BLOCKS, 256, 0, stream>>>(idxb, bcur, nlist);
  k_scompact<<<BF_BLOCKS, 256, 0, stream>>>(maskb, scur, slist);
  for (int e = 0; e < NEXP; e++) {
    k_layer1_rows<<<dim3((NN + 127) / 128, 2), 256, 0, stream>>>(
        Xb, Wt1, b0, idxb, slist, soff, e, Zb, A2);
    k_agg_z2<<<3125, 256, 0, stream>>>(Zb, offs, edge_src, nlist, boff, e, A2);
  }
  k_layer2_mfma<<<dim3(MAXT2, 2), 256, 0, stream>>>(
      A2, Wt2, b1, nlist, boff, tstart, outp);
}

// Round 7
// 612.241 us; speedup vs baseline: 1.1292x; 1.1292x over previous
//
#include <hip/hip_runtime.h>
#include <hip/hip_bf16.h>
#include <math.h>

#define NN 50000
#define NE 800000
#define NG 64
#define NEXP 8
#define ZC_CAP (3 * NN)

typedef __attribute__((ext_vector_type(8))) short bf16x8;
typedef __attribute__((ext_vector_type(4))) float f32x4;
typedef unsigned short ushort_t;

__device__ __forceinline__ unsigned short f2bf(float f) {
  union { float f; unsigned u; } x; x.f = f;
  unsigned r = x.u + 0x7fff + ((x.u >> 16) & 1);  // RNE
  return (unsigned short)(r >> 16);
}
__device__ __forceinline__ float bf2f(unsigned short u) {
  union { unsigned u; float f; } x; x.u = ((unsigned)u) << 16; return x.f;
}

__device__ __forceinline__ void gld16(const void* g, void* l) {
  __builtin_amdgcn_global_load_lds(
      (const __attribute__((address_space(1))) unsigned int*)g,
      (__attribute__((address_space(3))) unsigned int*)l, 16, 0, 0);
}

// -------- encoder: h = relu(x@W_enc+b); hi/lo bf16 split --------------------
__global__ __launch_bounds__(256) void k_encoder(
    const float* __restrict__ x, const float* __restrict__ W,
    const float* __restrict__ b, ushort_t* __restrict__ Xb,
    ushort_t* __restrict__ Xlo) {
  int i = blockIdx.x, n = threadIdx.x;
  float acc = b[n];
#pragma unroll
  for (int k = 0; k < 6; k++) acc = fmaf(x[i * 6 + k], W[k * 256 + n], acc);
  acc = fmaxf(acc, 0.f);
  unsigned short hb = f2bf(acc);
  Xb[(size_t)i * 512 + n] = hb;
  Xlo[(size_t)i * 256 + n] = f2bf(acc - bf2f(hb));  // bf16 residual (split-fp32)
}

// ---------------- per-graph node histogram ----------------
__global__ __launch_bounds__(256) void k_count_nodes(
    const int* __restrict__ batch, int* __restrict__ node_cnt) {
  __shared__ int bins[NG];
  int t = threadIdx.x;
  if (t < NG) bins[t] = 0;
  __syncthreads();
  for (int i = blockIdx.x * blockDim.x + t; i < NN; i += gridDim.x * blockDim.x)
    atomicAdd(&bins[batch[i]], 1);
  __syncthreads();
  if (t < NG) atomicAdd(&node_cnt[t], bins[t]);
}

// ---------------- per-graph edge histogram + in-degree ----------------
__global__ __launch_bounds__(256) void k_count_edges(
    const int* __restrict__ ei, const int* __restrict__ batch,
    int* __restrict__ edge_cnt, int* __restrict__ deg) {
  __shared__ int bins[NG];
  int t = threadIdx.x;
  if (t < NG) bins[t] = 0;
  __syncthreads();
  for (int e = blockIdx.x * blockDim.x + t; e < NE; e += gridDim.x * blockDim.x) {
    int s = ei[e];
    int d = ei[NE + e];
    atomicAdd(&bins[batch[s]], 1);
    atomicAdd(&deg[d], 1);
  }
  __syncthreads();
  if (t < NG) atomicAdd(&edge_cnt[t], bins[t]);
}

// ---------------- size features per node ----------------
__global__ __launch_bounds__(256) void k_sizefeat(
    const int* __restrict__ batch, const int* __restrict__ node_cnt,
    const int* __restrict__ edge_cnt, float* __restrict__ sf0,
    float* __restrict__ sf1) {
  int i = blockIdx.x * blockDim.x + threadIdx.x;
  if (i < NN) {
    int g = batch[i];
    sf0[i] = log1pf((float)node_cnt[g]);
    sf1[i] = log1pf((float)edge_cnt[g]);
  }
}

// ---------------- exclusive prefix scan of deg (single block) ----------------
__global__ __launch_bounds__(1024) void k_scan(
    const int* __restrict__ deg, int* __restrict__ offs, int* __restrict__ cursor) {
  __shared__ int wsums[16];
  int t = threadIdx.x, lane = t & 63, wid = t >> 6;
  int carry = 0;
  for (int base = 0; base < NN; base += 1024) {
    int i = base + t;
    int v = (i < NN) ? deg[i] : 0;
    int x = v;
#pragma unroll
    for (int d = 1; d < 64; d <<= 1) {
      int y = __shfl_up(x, d, 64);
      if (lane >= d) x += y;
    }
    if (lane == 63) wsums[wid] = x;
    __syncthreads();
    if (wid == 0) {
      int s = (lane < 16) ? wsums[lane] : 0;
#pragma unroll
      for (int d = 1; d < 16; d <<= 1) {
        int y = __shfl_up(s, d, 64);
        if (lane >= d) s += y;
      }
      if (lane < 16) wsums[lane] = s;
    }
    __syncthreads();
    int wpre = (wid > 0) ? wsums[wid - 1] : 0;
    int excl = carry + wpre + x - v;
    if (i < NN) { offs[i] = excl; cursor[i] = excl; }
    int btot = wsums[15];
    __syncthreads();
    carry += btot;
  }
  if (t == 0) offs[NN] = carry;
}

// ---------------- CSR fill: bucket edges by dst ----------------
__global__ __launch_bounds__(256) void k_fill_csr(
    const int* __restrict__ ei, int* __restrict__ cursor, int* __restrict__ edge_src) {
  int e = blockIdx.x * blockDim.x + threadIdx.x;
  if (e < NE) {
    int d = ei[NE + e];
    int pos = atomicAdd(&cursor[d], 1);
    edge_src[pos] = ei[e];
  }
}

// ------- A_h[i] = sum_{j in Nin(i)} h_bf[j] -> Xb[:, 256:512] (bf16) --------
__global__ __launch_bounds__(256) void k_agg_h2(
    const int* __restrict__ offs, const int* __restrict__ edge_src,
    ushort_t* __restrict__ Xb) {
  int wid = threadIdx.x >> 6, lane = threadIdx.x & 63;
  int half = lane >> 5, cl = lane & 31;
  int i = blockIdx.x * 4 + wid;
  if (i >= NN) return;
  int e0 = offs[i], e1 = offs[i + 1];
  float acc[8] = {};
  int k = e0;
  for (; k + 8 <= e1; k += 8) {
    int s0 = edge_src[k + half];
    int s1 = edge_src[k + 2 + half];
    int s2 = edge_src[k + 4 + half];
    int s3 = edge_src[k + 6 + half];
    bf16x8 v0 = *(const bf16x8*)&Xb[(size_t)s0 * 512 + cl * 8];
    bf16x8 v1 = *(const bf16x8*)&Xb[(size_t)s1 * 512 + cl * 8];
    bf16x8 v2 = *(const bf16x8*)&Xb[(size_t)s2 * 512 + cl * 8];
    bf16x8 v3 = *(const bf16x8*)&Xb[(size_t)s3 * 512 + cl * 8];
#pragma unroll
    for (int j = 0; j < 8; j++) acc[j] += bf2f((unsigned short)v0[j]);
#pragma unroll
    for (int j = 0; j < 8; j++) acc[j] += bf2f((unsigned short)v1[j]);
#pragma unroll
    for (int j = 0; j < 8; j++) acc[j] += bf2f((unsigned short)v2[j]);
#pragma unroll
    for (int j = 0; j < 8; j++) acc[j] += bf2f((unsigned short)v3[j]);
  }
  for (; k + 2 <= e1; k += 2) {
    int s0 = edge_src[k + half];
    bf16x8 v0 = *(const bf16x8*)&Xb[(size_t)s0 * 512 + cl * 8];
#pragma unroll
    for (int j = 0; j < 8; j++) acc[j] += bf2f((unsigned short)v0[j]);
  }
  if (k < e1 && half == 0) {
    int s0 = edge_src[k];
    bf16x8 v0 = *(const bf16x8*)&Xb[(size_t)s0 * 512 + cl * 8];
#pragma unroll
    for (int j = 0; j < 8; j++) acc[j] += bf2f((unsigned short)v0[j]);
  }
#pragma unroll
  for (int j = 0; j < 8; j++) acc[j] += __shfl_xor(acc[j], 32, 64);
  if (half == 0) {
    bf16x8 o;
#pragma unroll
    for (int j = 0; j < 8; j++) o[j] = (short)f2bf(acc[j]);
    *(bf16x8*)(&Xb[(size_t)i * 512 + 256 + cl * 8]) = o;
  }
}

// ------ Wt[e][n][k] bf16, k in [0,512): k<256 from Ws[e][k][n], else Wn ------
__global__ __launch_bounds__(256) void k_prep_w(
    const float* __restrict__ Ws0, const float* __restrict__ Wn0,
    const float* __restrict__ Ws1, const float* __restrict__ Wn1,
    ushort_t* __restrict__ Wt1, ushort_t* __restrict__ Wt2) {
  __shared__ float tile[32][33];
  int z = blockIdx.z;
  int e = z & 7;
  const float* Ws = (z < 8) ? Ws0 : Ws1;
  const float* Wn = (z < 8) ? Wn0 : Wn1;
  ushort_t* Wt = (z < 8) ? Wt1 : Wt2;
  int kt = blockIdx.x;
  int nt = blockIdx.y;
  int tx = threadIdx.x & 31, ty = threadIdx.x >> 5;
  const float* src = (kt < 8) ? (Ws + e * 65536 + (kt * 32) * 256)
                              : (Wn + e * 65536 + ((kt - 8) * 32) * 256);
#pragma unroll
  for (int rr = 0; rr < 32; rr += 8) {
    int k = rr + ty;
    tile[k][tx] = src[k * 256 + nt * 32 + tx];
  }
  __syncthreads();
#pragma unroll
  for (int rr = 0; rr < 32; rr += 8) {
    int n = rr + ty;
    Wt[(size_t)e * 131072 + (nt * 32 + n) * 512 + kt * 32 + tx] = f2bf(tile[tx][n]);
  }
}

// ------ router weight split: Wr1t[n][k], k<256 hi(Wr1), k<512 lo(Wr1) -------
__global__ __launch_bounds__(256) void k_prep_wr1(
    const float* __restrict__ Wr1, ushort_t* __restrict__ Wr1t) {
  int k = blockIdx.x;
  int n = threadIdx.x;
  unsigned short v;
  if (k < 256) {
    v = f2bf(Wr1[k * 256 + n]);
  } else {
    float f = Wr1[(k - 256) * 256 + n];
    unsigned short h = f2bf(f);
    v = f2bf(f - bf2f(h));
  }
  Wr1t[(size_t)n * 512 + k] = v;
}

// ------ router GEMM, split-bf16, R3 staging + 2-bit XOR swizzle -------------
// Swizzle: global chunk kc^(r&3) -> LDS slot kc (within 64B row-slice; same
// cache lines => coalescing preserved). Read slot = q16^(ra&3). 8-way -> 4-way.
#define TIE_TAU 1e-4f
__global__ __launch_bounds__(256) void k_router_mfma(
    const ushort_t* __restrict__ Xb,    // [NN][512], cols 0..255 = hi(h)
    const ushort_t* __restrict__ Xlo,   // [NN][256] = lo(h)
    const ushort_t* __restrict__ Wr1t,  // [256][512] bf16 (n-major, hi|lo)
    const float* __restrict__ Wr1, const float* __restrict__ br1,
    const float* __restrict__ Wr2, const float* __restrict__ sf0,
    const float* __restrict__ sf1, float* __restrict__ Lpart) {
  __shared__ ushort_t As[2][4096];
  __shared__ ushort_t Bs1[2][4096];
  __shared__ ushort_t Bs2[2][4096];
  __shared__ float Lsm[128][NEXP];
  int t = threadIdx.x;
  int w = t >> 6, lane = t & 63;
  int m0 = blockIdx.x * 128;
  int n0 = blockIdx.y * 128;
  int wm = w >> 1, wn = w & 1;
  int q16 = lane >> 4, c15 = lane & 15;
  for (int z = t; z < 128 * NEXP; z += 256) ((float*)Lsm)[z] = 0.f;

  auto STAGE = [&](int s, int kt) {
    int k0 = (kt & 7) * 32;
    bool hi = kt < 8;
#pragma unroll
    for (int i = 0; i < 2; i++) {
      int c = w * 128 + i * 64 + lane;
      int r = c >> 2, kc = c & 3;
      int kcs = kc ^ (r & 3);   // pre-swizzled source chunk (same 64B line set)
      int gr = m0 + r; if (gr >= NN) gr = NN - 1;
      int dst = (w * 128 + i * 64) * 8;
      if (hi) {
        gld16(Xb + (size_t)gr * 512 + k0 + kcs * 8, (void*)&As[s][dst]);
        gld16(Wr1t + (size_t)(n0 + r) * 512 + k0 + kcs * 8, (void*)&Bs1[s][dst]);
        gld16(Wr1t + (size_t)(n0 + r) * 512 + 256 + k0 + kcs * 8, (void*)&Bs2[s][dst]);
      } else {
        gld16(Xlo + (size_t)gr * 256 + k0 + kcs * 8, (void*)&As[s][dst]);
        gld16(Wr1t + (size_t)(n0 + r) * 512 + k0 + kcs * 8, (void*)&Bs1[s][dst]);
      }
    }
  };

  f32x4 acc[4][4] = {};
  STAGE(0, 0);
  __syncthreads();
  for (int kt = 0; kt < 16; kt++) {
    int cur = kt & 1;
    if (kt < 15) STAGE(cur ^ 1, kt + 1);
    bf16x8 a[4], b1[4];
#pragma unroll
    for (int i = 0; i < 4; i++) {
      int ra = wm * 64 + i * 16 + c15;
      a[i] = *(const bf16x8*)&As[cur][ra * 32 + (q16 ^ (ra & 3)) * 8];
      int nb = wn * 64 + i * 16 + c15;
      b1[i] = *(const bf16x8*)&Bs1[cur][nb * 32 + (q16 ^ (nb & 3)) * 8];
    }
#pragma unroll
    for (int i = 0; i < 4; i++)
#pragma unroll
      for (int j = 0; j < 4; j++)
        acc[i][j] = __builtin_amdgcn_mfma_f32_16x16x32_bf16(a[i], b1[j], acc[i][j], 0, 0, 0);
    if (kt < 8) {
      bf16x8 b2[4];
#pragma unroll
      for (int i = 0; i < 4; i++) {
        int nb = wn * 64 + i * 16 + c15;
        b2[i] = *(const bf16x8*)&Bs2[cur][nb * 32 + (q16 ^ (nb & 3)) * 8];
      }
#pragma unroll
      for (int i = 0; i < 4; i++)
#pragma unroll
        for (int j = 0; j < 4; j++)
          acc[i][j] = __builtin_amdgcn_mfma_f32_16x16x32_bf16(a[i], b2[j], acc[i][j], 0, 0, 0);
    }
    __syncthreads();
  }

  float bb[4], w6[4], w7[4];
#pragma unroll
  for (int j = 0; j < 4; j++) {
    int col = n0 + wn * 64 + j * 16 + c15;
    bb[j] = br1[col];
    w6[j] = Wr1[65536 + col];
    w7[j] = Wr1[65792 + col];
  }
#pragma unroll
  for (int i = 0; i < 4; i++)
#pragma unroll
    for (int v = 0; v < 4; v++) {
      int row = m0 + wm * 64 + i * 16 + q16 * 4 + v;
      float s0v = (row < NN) ? sf0[row] : 0.f;
      float s1v = (row < NN) ? sf1[row] : 0.f;
#pragma unroll
      for (int j = 0; j < 4; j++)
        acc[i][j][v] = fmaxf(acc[i][j][v] + bb[j] + s0v * w6[j] + s1v * w7[j], 0.f);
    }
#pragma unroll
  for (int e = 0; e < NEXP; e++) {
    float wr2j[4];
#pragma unroll
    for (int j = 0; j < 4; j++)
      wr2j[j] = Wr2[(n0 + wn * 64 + j * 16 + c15) * 8 + e];
    float pe[4][4];
#pragma unroll
    for (int i = 0; i < 4; i++)
#pragma unroll
      for (int v = 0; v < 4; v++) {
        float s = acc[i][0][v] * wr2j[0];
        s = fmaf(acc[i][1][v], wr2j[1], s);
        s = fmaf(acc[i][2][v], wr2j[2], s);
        s = fmaf(acc[i][3][v], wr2j[3], s);
        pe[i][v] = s;
      }
#pragma unroll
    for (int d = 1; d < 16; d <<= 1)
#pragma unroll
      for (int i = 0; i < 4; i++)
#pragma unroll
        for (int v = 0; v < 4; v++)
          pe[i][v] += __shfl_xor(pe[i][v], d, 64);
    if (c15 == 0) {
#pragma unroll
      for (int i = 0; i < 4; i++)
#pragma unroll
        for (int v = 0; v < 4; v++)
          atomicAdd(&Lsm[wm * 64 + i * 16 + q16 * 4 + v][e], pe[i][v]);
    }
  }
  __syncthreads();
  for (int z = t; z < 128 * NEXP; z += 256) {
    int lr = z >> 3, e = z & 7;
    int row = m0 + lr;
    if (row < NN)
      Lpart[(size_t)blockIdx.y * (NN * 8) + (size_t)row * 8 + e] = Lsm[lr][e];
  }
}

// ------ argmax over fused partial logits; near-ties queued for fixup --------
__global__ __launch_bounds__(256) void k_argmax(
    const float* __restrict__ Lpart, const float* __restrict__ br2,
    int* __restrict__ idx, int* __restrict__ nfix, int* __restrict__ fixlist) {
  int i = blockIdx.x * 256 + threadIdx.x;
  if (i >= NN) return;
  float best = -1e30f, second = -1e30f; int bi = 0;
#pragma unroll
  for (int e = 0; e < NEXP; e++) {
    float v = br2[e] + Lpart[(size_t)i * 8 + e]
              + Lpart[(size_t)(NN * 8) + (size_t)i * 8 + e];
    if (v > best) { second = best; best = v; bi = e; }  // strict >: first-wins
    else if (v > second) second = v;
  }
  idx[i] = bi;
  if (best - second < TIE_TAU) {
    int p = atomicAdd(nfix, 1);
    fixlist[p] = i;
  }
}

// ------ fp32 re-route for near-tie nodes (recomputes h from x) --------------
__global__ __launch_bounds__(256) void k_fixup(
    const float* __restrict__ x, const float* __restrict__ W_enc,
    const float* __restrict__ b_enc, const float* __restrict__ Wr1,
    const float* __restrict__ br1, const float* __restrict__ Wr2,
    const float* __restrict__ br2, const float* __restrict__ sf0,
    const float* __restrict__ sf1, const int* __restrict__ fixlist,
    const int* __restrict__ nfix, int* __restrict__ idx) {
  __shared__ float hsh[256];
  __shared__ float lred[4][NEXP];
  int n = *nfix;
  int t = threadIdx.x, wid = t >> 6, lane = t & 63;
  for (int qq = blockIdx.x; qq < n; qq += gridDim.x) {
    int node = fixlist[qq];
    float hv = b_enc[t];
#pragma unroll
    for (int k = 0; k < 6; k++)
      hv = fmaf(x[node * 6 + k], W_enc[k * 256 + t], hv);
    hsh[t] = fmaxf(hv, 0.f);
    __syncthreads();
    float acc = br1[t] + sf0[node] * Wr1[65536 + t] + sf1[node] * Wr1[65792 + t];
    for (int k = 0; k < 256; k++)
      acc = fmaf(hsh[k], Wr1[k * 256 + t], acc);
    float r = fmaxf(acc, 0.f);
    float le[NEXP];
#pragma unroll
    for (int e = 0; e < NEXP; e++) le[e] = r * Wr2[t * 8 + e];
#pragma unroll
    for (int d = 32; d > 0; d >>= 1)
#pragma unroll
      for (int e = 0; e < NEXP; e++) le[e] += __shfl_xor(le[e], d, 64);
    if (lane == 0) {
#pragma unroll
      for (int e = 0; e < NEXP; e++) lred[wid][e] = le[e];
    }
    __syncthreads();
    if (t == 0) {
      float best = -1e30f; int bi = 0;
      for (int e = 0; e < NEXP; e++) {
        float v = lred[0][e] + lred[1][e] + lred[2][e] + lred[3][e] + br2[e];
        if (v > best) { best = v; bi = e; }
      }
      idx[node] = bi;
    }
    __syncthreads();
  }
}

// ------ expert histogram ------
__global__ __launch_bounds__(256) void k_ecnt(
    const int* __restrict__ idx, int* __restrict__ ecnt) {
  __shared__ int bins[NEXP];
  int t = threadIdx.x;
  if (t < NEXP) bins[t] = 0;
  __syncthreads();
  for (int i = blockIdx.x * 256 + t; i < NN; i += gridDim.x * 256)
    atomicAdd(&bins[idx[i]], 1);
  __syncthreads();
  if (t < NEXP) atomicAdd(&ecnt[t], bins[t]);
}

// ------ source mask: mask[j] bit e set iff z_e[j] is needed ------
__global__ __launch_bounds__(256) void k_srcmask(
    const int* __restrict__ ei, const int* __restrict__ idx,
    unsigned int* __restrict__ mask) {
  int k = blockIdx.x * 256 + threadIdx.x;
  if (k < NE) {
    int s = ei[k], d = ei[NE + k];
    atomicOr(&mask[s], 1u << idx[d]);
  }
  if (k < NN) atomicOr(&mask[k], 1u << idx[k]);  // self bit
}

// ------ per-expert source-list sizes ------
__global__ __launch_bounds__(256) void k_scount(
    const unsigned int* __restrict__ mask, int* __restrict__ scnt) {
  __shared__ int bins[NEXP];
  int t = threadIdx.x;
  if (t < NEXP) bins[t] = 0;
  __syncthreads();
  for (int i = blockIdx.x * 256 + t; i < NN; i += gridDim.x * 256) {
    unsigned m = mask[i];
    while (m) { int b = __ffs(m) - 1; atomicAdd(&bins[b], 1); m &= m - 1; }
  }
  __syncthreads();
  if (t < NEXP) atomicAdd(&scnt[t], bins[t]);
}

// boff/bcur + tile starts + source-list offsets + layer1 tile table
__global__ void k_bucket_offs(const int* __restrict__ ecnt,
                              const int* __restrict__ scnt,
                              int* __restrict__ boff, int* __restrict__ bcur,
                              int* __restrict__ tstart,
                              int* __restrict__ soff, int* __restrict__ scur,
                              int* __restrict__ ltstart) {
  if (threadIdx.x == 0) {
    int s = 0, ts = 0, s2 = 0, lt = 0;
    for (int e = 0; e < NEXP; e++) {
      boff[e] = s; bcur[e] = s;
      tstart[e] = ts;
      ts += (ecnt[e] + 127) / 128;
      s += ecnt[e];
      soff[e] = s2; scur[e] = s2;
      ltstart[e] = lt;
      lt += (scnt[e] + 127) / 128;
      s2 += scnt[e];
    }
    boff[NEXP] = s;
    tstart[NEXP] = ts;
    soff[NEXP] = s2;
    ltstart[NEXP] = lt;
  }
}

// ---- block-aggregated bucket fill ----
#define BF_BLOCKS 64
__global__ __launch_bounds__(256) void k_bucket_fill2(
    const int* __restrict__ idx, int* __restrict__ bcur, int* __restrict__ nlist) {
  __shared__ int lcnt[NEXP];
  __shared__ int lbase[NEXP];
  int t = threadIdx.x;
  int chunk = (NN + BF_BLOCKS - 1) / BF_BLOCKS;
  int lo = blockIdx.x * chunk;
  int hi = lo + chunk; if (hi > NN) hi = NN;
  if (t < NEXP) lcnt[t] = 0;
  __syncthreads();
  for (int i = lo + t; i < hi; i += 256) atomicAdd(&lcnt[idx[i]], 1);
  __syncthreads();
  if (t < NEXP) lbase[t] = atomicAdd(&bcur[t], lcnt[t]);
  __syncthreads();
  if (t < NEXP) lcnt[t] = 0;
  __syncthreads();
  for (int i = lo + t; i < hi; i += 256) {
    int e = idx[i];
    int p = atomicAdd(&lcnt[e], 1);
    nlist[lbase[e] + p] = i;
  }
}

// ---- compact per-expert source lists from mask; also inverse map -----------
__global__ __launch_bounds__(256) void k_scompact(
    const unsigned int* __restrict__ mask, int* __restrict__ scur,
    int* __restrict__ slist, int* __restrict__ posmap) {
  __shared__ int lcnt[NEXP];
  __shared__ int lbase[NEXP];
  int t = threadIdx.x;
  int chunk = (NN + BF_BLOCKS - 1) / BF_BLOCKS;
  int lo = blockIdx.x * chunk;
  int hi = lo + chunk; if (hi > NN) hi = NN;
  if (t < NEXP) lcnt[t] = 0;
  __syncthreads();
  for (int i = lo + t; i < hi; i += 256) {
    unsigned m = mask[i];
    while (m) { int b = __ffs(m) - 1; atomicAdd(&lcnt[b], 1); m &= m - 1; }
  }
  __syncthreads();
  if (t < NEXP) lbase[t] = atomicAdd(&scur[t], lcnt[t]);
  __syncthreads();
  if (t < NEXP) lcnt[t] = 0;
  __syncthreads();
  for (int i = lo + t; i < hi; i += 256) {
    unsigned m = mask[i];
    while (m) {
      int b = __ffs(m) - 1;
      int p = atomicAdd(&lcnt[b], 1);
      int gp = lbase[b] + p;
      slist[gp] = i;
      posmap[(size_t)b * NN + i] = (gp < ZC_CAP) ? gp : 0;  // clamp (safety)
      m &= m - 1;
    }
  }
}

// ------- layer1 ALL experts, one dispatch; swizzled LDS; writes Zc ----------
#define MAXT1 (8 * 391 + 8)
__global__ __launch_bounds__(256) void k_layer1_all(
    const ushort_t* __restrict__ Abf,  // Xb [NN][512] bf16
    const ushort_t* __restrict__ Wt,   // [8][256][512] bf16 (n-major)
    const float* __restrict__ b0, const int* __restrict__ idx,
    const int* __restrict__ slist, const int* __restrict__ soff,
    const int* __restrict__ ltstart,
    ushort_t* __restrict__ Zc, ushort_t* __restrict__ A2) {
  int tx = blockIdx.x;
  int e = -1;
#pragma unroll
  for (int q = 0; q < NEXP; q++)
    if (tx >= ltstart[q] && tx < ltstart[q + 1]) e = q;
  if (e < 0) return;
  int tile = tx - ltstart[e];
  int base = soff[e];
  int cnt = soff[e + 1] - base;
  int m0 = tile * 128;
  __shared__ ushort_t As[2][4096];
  __shared__ ushort_t Bs[2][4096];
  __shared__ int rows[128];
  __shared__ int sidx[128];
  int t = threadIdx.x;
  if (t < 128) {
    int r = (m0 + t < cnt) ? slist[base + m0 + t] : -1;
    rows[t] = r;
    sidx[t] = (r >= 0) ? idx[r] : -1;
  }
  __syncthreads();
  int w = t >> 6, lane = t & 63;
  int n0 = blockIdx.y * 128;
  int wm = w >> 1, wn = w & 1;
  int q16 = lane >> 4, c15 = lane & 15;
  const ushort_t* Wb = Wt + (size_t)e * 131072;

  auto STAGE = [&](int s, int kt) {
    int k0 = kt * 32;
#pragma unroll
    for (int i = 0; i < 2; i++) {
      int c = w * 128 + i * 64 + lane;
      int r = c >> 2, kc = c & 3;
      int kcs = kc ^ (r & 3);
      int nd = rows[r]; if (nd < 0) nd = 0;
      int dst = (w * 128 + i * 64) * 8;
      gld16(Abf + (size_t)nd * 512 + k0 + kcs * 8, (void*)&As[s][dst]);
      gld16(Wb + (size_t)(n0 + r) * 512 + k0 + kcs * 8, (void*)&Bs[s][dst]);
    }
  };

  f32x4 acc[4][4] = {};
  STAGE(0, 0);
  __syncthreads();
  for (int kt = 0; kt < 16; kt++) {
    int cur = kt & 1;
    if (kt < 15) STAGE(cur ^ 1, kt + 1);
    bf16x8 a[4], b[4];
#pragma unroll
    for (int i = 0; i < 4; i++) {
      int ra = wm * 64 + i * 16 + c15;
      a[i] = *(const bf16x8*)&As[cur][ra * 32 + (q16 ^ (ra & 3)) * 8];
      int nb = wn * 64 + i * 16 + c15;
      b[i] = *(const bf16x8*)&Bs[cur][nb * 32 + (q16 ^ (nb & 3)) * 8];
    }
#pragma unroll
    for (int i = 0; i < 4; i++)
#pragma unroll
      for (int j = 0; j < 4; j++)
        acc[i][j] = __builtin_amdgcn_mfma_f32_16x16x32_bf16(a[i], b[j], acc[i][j], 0, 0, 0);
    __syncthreads();
  }
#pragma unroll
  for (int i = 0; i < 4; i++) {
#pragma unroll
    for (int j = 0; j < 4; j++) {
      int col = n0 + wn * 64 + j * 16 + c15;
      float bias = b0[e * 256 + col];
#pragma unroll
      for (int v = 0; v < 4; v++) {
        int lrow = wm * 64 + i * 16 + q16 * 4 + v;
        int node = rows[lrow];
        if (node >= 0) {
          unsigned short zb = f2bf(fmaxf(acc[i][j][v] + bias, 0.f));
          int sp = base + m0 + lrow;
          if (sp < ZC_CAP) Zc[(size_t)sp * 256 + col] = zb;
          if (sidx[lrow] == e) A2[(size_t)node * 512 + col] = zb;
        }
      }
    }
  }
}

// ---- agg_z ALL buckets, one persistent dispatch (posmap indirection) -------
__global__ __launch_bounds__(256) void k_agg_z_all(
    const ushort_t* __restrict__ Zc, const int* __restrict__ offs,
    const int* __restrict__ edge_src, const int* __restrict__ nlist,
    const int* __restrict__ boff, const int* __restrict__ posmap,
    ushort_t* __restrict__ A2) {
  int wid = threadIdx.x >> 6, lane = threadIdx.x & 63;
  int half = lane >> 5, cl = lane & 31;
  for (int b = blockIdx.x * 4 + wid; b < NN; b += gridDim.x * 4) {
    int e = 0;
#pragma unroll
    for (int q = 1; q < NEXP; q++)
      if (b >= boff[q]) e = q;
    int i = nlist[b];
    const int* pm = posmap + (size_t)e * NN;
    int e0 = offs[i], e1 = offs[i + 1];
    float acc[8] = {};
    int k = e0;
    for (; k + 8 <= e1; k += 8) {
      int s0 = edge_src[k + half];
      int s1 = edge_src[k + 2 + half];
      int s2 = edge_src[k + 4 + half];
      int s3 = edge_src[k + 6 + half];
      int p0 = pm[s0], p1 = pm[s1], p2 = pm[s2], p3 = pm[s3];
      bf16x8 v0 = *(const bf16x8*)&Zc[(size_t)p0 * 256 + cl * 8];
      bf16x8 v1 = *(const bf16x8*)&Zc[(size_t)p1 * 256 + cl * 8];
      bf16x8 v2 = *(const bf16x8*)&Zc[(size_t)p2 * 256 + cl * 8];
      bf16x8 v3 = *(const bf16x8*)&Zc[(size_t)p3 * 256 + cl * 8];
#pragma unroll
      for (int j = 0; j < 8; j++) acc[j] += bf2f((unsigned short)v0[j]);
#pragma unroll
      for (int j = 0; j < 8; j++) acc[j] += bf2f((unsigned short)v1[j]);
#pragma unroll
      for (int j = 0; j < 8; j++) acc[j] += bf2f((unsigned short)v2[j]);
#pragma unroll
      for (int j = 0; j < 8; j++) acc[j] += bf2f((unsigned short)v3[j]);
    }
    for (; k + 2 <= e1; k += 2) {
      int s0 = edge_src[k + half];
      int p0 = pm[s0];
      bf16x8 v0 = *(const bf16x8*)&Zc[(size_t)p0 * 256 + cl * 8];
#pragma unroll
      for (int j = 0; j < 8; j++) acc[j] += bf2f((unsigned short)v0[j]);
    }
    if (k < e1 && half == 0) {
      int s0 = edge_src[k];
      int p0 = pm[s0];
      bf16x8 v0 = *(const bf16x8*)&Zc[(size_t)p0 * 256 + cl * 8];
#pragma unroll
      for (int j = 0; j < 8; j++) acc[j] += bf2f((unsigned short)v0[j]);
    }
#pragma unroll
    for (int j = 0; j < 8; j++) acc[j] += __shfl_xor(acc[j], 32, 64);
    if (half == 0) {
      bf16x8 o;
#pragma unroll
      for (int j = 0; j < 8; j++) o[j] = (short)f2bf(acc[j]);
      *(bf16x8*)(&A2[(size_t)i * 512 + 256 + cl * 8]) = o;
    }
  }
}

// ------- fused layer2 MFMA over all buckets, swizzled LDS -------------------
#define MAXT2 (391 + NEXP)
__global__ __launch_bounds__(256) void k_layer2_mfma(
    const ushort_t* __restrict__ A2,   // [NN][512] bf16
    const ushort_t* __restrict__ Wt,   // [8][256][512] bf16 (n-major)
    const float* __restrict__ b1, const int* __restrict__ nlist,
    const int* __restrict__ boff, const int* __restrict__ tstart,
    float* __restrict__ outp) {
  __shared__ ushort_t As[2][4096];
  __shared__ ushort_t Bs[2][4096];
  __shared__ int rows[128];
  int t = threadIdx.x;
  int tx = blockIdx.x;
  int e = -1;
#pragma unroll
  for (int q = 0; q < NEXP; q++)
    if (tx >= tstart[q] && tx < tstart[q + 1]) e = q;
  if (e < 0) return;
  int tile = tx - tstart[e];
  int base = boff[e];
  int cnt = boff[e + 1] - base;
  int m0 = tile * 128;
  if (t < 128) rows[t] = (m0 + t < cnt) ? nlist[base + m0 + t] : -1;
  __syncthreads();
  int w = t >> 6, lane = t & 63;
  int n0 = blockIdx.y * 128;
  int wm = w >> 1, wn = w & 1;
  int q16 = lane >> 4, c15 = lane & 15;
  const ushort_t* Wb = Wt + (size_t)e * 131072;

  auto STAGE = [&](int s, int kt) {
    int k0 = kt * 32;
#pragma unroll
    for (int i = 0; i < 2; i++) {
      int c = w * 128 + i * 64 + lane;
      int r = c >> 2, kc = c & 3;
      int kcs = kc ^ (r & 3);
      int nd = rows[r]; if (nd < 0) nd = 0;
      int dst = (w * 128 + i * 64) * 8;
      gld16(A2 + (size_t)nd * 512 + k0 + kcs * 8, (void*)&As[s][dst]);
      gld16(Wb + (size_t)(n0 + r) * 512 + k0 + kcs * 8, (void*)&Bs[s][dst]);
    }
  };

  f32x4 acc[4][4] = {};
  STAGE(0, 0);
  __syncthreads();
  for (int kt = 0; kt < 16; kt++) {
    int cur = kt & 1;
    if (kt < 15) STAGE(cur ^ 1, kt + 1);
    bf16x8 a[4], b[4];
#pragma unroll
    for (int i = 0; i < 4; i++) {
      int ra = wm * 64 + i * 16 + c15;
      a[i] = *(const bf16x8*)&As[cur][ra * 32 + (q16 ^ (ra & 3)) * 8];
      int nb = wn * 64 + i * 16 + c15;
      b[i] = *(const bf16x8*)&Bs[cur][nb * 32 + (q16 ^ (nb & 3)) * 8];
    }
#pragma unroll
    for (int i = 0; i < 4; i++)
#pragma unroll
      for (int j = 0; j < 4; j++)
        acc[i][j] = __builtin_amdgcn_mfma_f32_16x16x32_bf16(a[i], b[j], acc[i][j], 0, 0, 0);
    __syncthreads();
  }
#pragma unroll
  for (int i = 0; i < 4; i++) {
#pragma unroll
    for (int j = 0; j < 4; j++) {
      int col = n0 + wn * 64 + j * 16 + c15;
      float bias = b1[e * 256 + col];
#pragma unroll
      for (int v = 0; v < 4; v++) {
        int lrow = wm * 64 + i * 16 + q16 * 4 + v;
        int node = rows[lrow];
        if (node >= 0) outp[(size_t)node * 256 + col] = acc[i][j][v] + bias;
      }
    }
  }
}

static inline char* wsalloc(char*& p, size_t bytes) {
  char* r = p;
  p += (bytes + 255) & ~(size_t)255;
  return r;
}

extern "C" void kernel_launch(void* const* d_in, const int* in_sizes, int n_in,
                              void* d_out, int out_size, void* d_ws, size_t ws_size,
                              hipStream_t stream) {
  const float* x     = (const float*)d_in[0];
  const int*   ei    = (const int*)d_in[1];
  const int*   batch = (const int*)d_in[2];
  const float* W_enc = (const float*)d_in[3];
  const float* b_enc = (const float*)d_in[4];
  const float* Wr1   = (const float*)d_in[5];
  const float* br1   = (const float*)d_in[6];
  const float* Wr2   = (const float*)d_in[7];
  const float* br2   = (const float*)d_in[8];
  const float* Ws0   = (const float*)d_in[9];
  const float* Wn0   = (const float*)d_in[10];
  const float* b0    = (const float*)d_in[11];
  const float* Ws1   = (const float*)d_in[12];
  const float* Wn1   = (const float*)d_in[13];
  const float* b1    = (const float*)d_in[14];
  float* outp = (float*)d_out;

  char* p = (char*)d_ws;
  ushort_t* Xb   = (ushort_t*)wsalloc(p, (size_t)NN * 512 * 2);     // [h | A_h]
  ushort_t* Zc   = (ushort_t*)wsalloc(p, (size_t)ZC_CAP * 256 * 2); // compact z
  ushort_t* A2   = (ushort_t*)wsalloc(p, (size_t)NN * 512 * 2);     // [z_self | agg]
  ushort_t* Xlo  = Zc;             // alias: Xlo dies (router) before Zc born (layer1)
  float*    Lpart= (float*)wsalloc(p, (size_t)2 * NN * 8 * 4);
  ushort_t* Wt1  = (ushort_t*)wsalloc(p, (size_t)NEXP * 256 * 512 * 2);
  ushort_t* Wt2  = (ushort_t*)wsalloc(p, (size_t)NEXP * 256 * 512 * 2);
  ushort_t* Wr1t = (ushort_t*)wsalloc(p, (size_t)256 * 512 * 2);
  int* edge_src  = (int*)wsalloc(p, (size_t)NE * 4);
  int* offs      = (int*)wsalloc(p, (size_t)(NN + 1) * 4);
  int* cursor    = (int*)wsalloc(p, (size_t)NN * 4);
  int* deg       = (int*)wsalloc(p, (size_t)NN * 4);
  int* idxb      = (int*)wsalloc(p, (size_t)NN * 4);
  float* sf0     = (float*)wsalloc(p, (size_t)NN * 4);
  float* sf1     = (float*)wsalloc(p, (size_t)NN * 4);
  int* nlist     = (int*)wsalloc(p, (size_t)NN * 4);
  int* fixlist   = (int*)wsalloc(p, (size_t)NN * 4);
  unsigned int* maskb = (unsigned int*)wsalloc(p, (size_t)NN * 4);
  int* slist     = (int*)wsalloc(p, (size_t)NN * NEXP * 4);
  int* posmap    = (int*)wsalloc(p, (size_t)NN * NEXP * 4);
  int* smallb    = (int*)wsalloc(p, 256 * 4);
  int* node_cnt = smallb;        // 64
  int* edge_cnt = smallb + 64;   // 64
  int* ecnt     = smallb + 128;  // 8
  int* boff     = smallb + 136;  // 9
  int* bcur     = smallb + 152;  // 8
  int* tstart   = smallb + 160;  // 9
  int* nfix     = smallb + 192;  // 1
  int* scnt     = smallb + 200;  // 8
  int* soff     = smallb + 208;  // 9
  int* scur     = smallb + 224;  // 8
  int* ltstart  = smallb + 232;  // 9

  hipMemsetAsync(deg, 0, (size_t)NN * 4, stream);
  hipMemsetAsync(smallb, 0, 256 * 4, stream);
  hipMemsetAsync(maskb, 0, (size_t)NN * 4, stream);

  k_encoder<<<NN, 256, 0, stream>>>(x, W_enc, b_enc, Xb, Xlo);
  k_count_nodes<<<64, 256, 0, stream>>>(batch, node_cnt);
  k_count_edges<<<128, 256, 0, stream>>>(ei, batch, edge_cnt, deg);
  k_sizefeat<<<(NN + 255) / 256, 256, 0, stream>>>(batch, node_cnt, edge_cnt, sf0, sf1);
  k_scan<<<1, 1024, 0, stream>>>(deg, offs, cursor);
  k_fill_csr<<<(NE + 255) / 256, 256, 0, stream>>>(ei, cursor, edge_src);
  k_agg_h2<<<(NN + 3) / 4, 256, 0, stream>>>(offs, edge_src, Xb);
  k_prep_w<<<dim3(16, 8, 16), 256, 0, stream>>>(Ws0, Wn0, Ws1, Wn1, Wt1, Wt2);
  k_prep_wr1<<<512, 256, 0, stream>>>(Wr1, Wr1t);
  k_router_mfma<<<dim3((NN + 127) / 128, 2), 256, 0, stream>>>(
      Xb, Xlo, Wr1t, Wr1, br1, Wr2, sf0, sf1, Lpart);
  k_argmax<<<(NN + 255) / 256, 256, 0, stream>>>(Lpart, br2, idxb, nfix, fixlist);
  k_fixup<<<256, 256, 0, stream>>>(x, W_enc, b_enc, Wr1, br1, Wr2, br2,
                                   sf0, sf1, fixlist, nfix, idxb);
  k_srcmask<<<(NE + 255) / 256, 256, 0, stream>>>(ei, idxb, maskb);
  k_ecnt<<<64, 256, 0, stream>>>(idxb, ecnt);
  k_scount<<<64, 256, 0, stream>>>(maskb, scnt);
  k_bucket_offs<<<1, 64, 0, stream>>>(ecnt, scnt, boff, bcur, tstart, soff, scur, ltstart);
  k_bucket_fill2<<<BF_BLOCKS, 256, 0, stream>>>(idxb, bcur, nlist);
  k_scompact<<<BF_BLOCKS, 256, 0, stream>>>(maskb, scur, slist, posmap);
  k_layer1_all<<<dim3(MAXT1, 2), 256, 0, stream>>>(
      Xb, Wt1, b0, idxb, slist, soff, ltstart, Zc, A2);
  k_agg_z_all<<<3125, 256, 0, stream>>>(Zc, offs, edge_src, nlist, boff, posmap, A2);
  k_layer2_mfma<<<dim3(MAXT2, 2), 256, 0, stream>>>(
      A2, Wt2, b1, nlist, boff, tstart, outp);
}

// Round 8
// 587.978 us; speedup vs baseline: 1.1758x; 1.0413x over previous
//
#include <hip/hip_runtime.h>
#include <hip/hip_bf16.h>
#include <math.h>

#define NN 50000
#define NE 800000
#define NG 64
#define NEXP 8
#define ZC_CAP (3 * NN)

typedef __attribute__((ext_vector_type(8))) short bf16x8;
typedef __attribute__((ext_vector_type(8))) _Float16 f16x8;
typedef __attribute__((ext_vector_type(4))) float f32x4;
typedef unsigned short ushort_t;

__device__ __forceinline__ unsigned short f2bf(float f) {
  union { float f; unsigned u; } x; x.f = f;
  unsigned r = x.u + 0x7fff + ((x.u >> 16) & 1);  // RNE
  return (unsigned short)(r >> 16);
}
__device__ __forceinline__ float bf2f(unsigned short u) {
  union { unsigned u; float f; } x; x.u = ((unsigned)u) << 16; return x.f;
}

__device__ __forceinline__ void gld16(const void* g, void* l) {
  __builtin_amdgcn_global_load_lds(
      (const __attribute__((address_space(1))) unsigned int*)g,
      (__attribute__((address_space(3))) unsigned int*)l, 16, 0, 0);
}

// -------- encoder: h = relu(x@W_enc+b); bf16 (pipeline) + fp16 (router) ----
__global__ __launch_bounds__(256) void k_encoder(
    const float* __restrict__ x, const float* __restrict__ W,
    const float* __restrict__ b, ushort_t* __restrict__ Xb,
    _Float16* __restrict__ Xh16) {
  int i = blockIdx.x, n = threadIdx.x;
  float acc = b[n];
#pragma unroll
  for (int k = 0; k < 6; k++) acc = fmaf(x[i * 6 + k], W[k * 256 + n], acc);
  acc = fmaxf(acc, 0.f);
  Xb[(size_t)i * 512 + n] = f2bf(acc);
  Xh16[(size_t)i * 256 + n] = (_Float16)acc;   // router operand (10-bit mantissa)
}

// ---------------- per-graph node histogram ----------------
__global__ __launch_bounds__(256) void k_count_nodes(
    const int* __restrict__ batch, int* __restrict__ node_cnt) {
  __shared__ int bins[NG];
  int t = threadIdx.x;
  if (t < NG) bins[t] = 0;
  __syncthreads();
  for (int i = blockIdx.x * blockDim.x + t; i < NN; i += gridDim.x * blockDim.x)
    atomicAdd(&bins[batch[i]], 1);
  __syncthreads();
  if (t < NG) atomicAdd(&node_cnt[t], bins[t]);
}

// ---------------- per-graph edge histogram + in-degree ----------------
__global__ __launch_bounds__(256) void k_count_edges(
    const int* __restrict__ ei, const int* __restrict__ batch,
    int* __restrict__ edge_cnt, int* __restrict__ deg) {
  __shared__ int bins[NG];
  int t = threadIdx.x;
  if (t < NG) bins[t] = 0;
  __syncthreads();
  for (int e = blockIdx.x * blockDim.x + t; e < NE; e += gridDim.x * blockDim.x) {
    int s = ei[e];
    int d = ei[NE + e];
    atomicAdd(&bins[batch[s]], 1);
    atomicAdd(&deg[d], 1);
  }
  __syncthreads();
  if (t < NG) atomicAdd(&edge_cnt[t], bins[t]);
}

// ---------------- size features per node ----------------
__global__ __launch_bounds__(256) void k_sizefeat(
    const int* __restrict__ batch, const int* __restrict__ node_cnt,
    const int* __restrict__ edge_cnt, float* __restrict__ sf0,
    float* __restrict__ sf1) {
  int i = blockIdx.x * blockDim.x + threadIdx.x;
  if (i < NN) {
    int g = batch[i];
    sf0[i] = log1pf((float)node_cnt[g]);
    sf1[i] = log1pf((float)edge_cnt[g]);
  }
}

// ---------------- exclusive prefix scan of deg (single block) ----------------
__global__ __launch_bounds__(1024) void k_scan(
    const int* __restrict__ deg, int* __restrict__ offs, int* __restrict__ cursor) {
  __shared__ int wsums[16];
  int t = threadIdx.x, lane = t & 63, wid = t >> 6;
  int carry = 0;
  for (int base = 0; base < NN; base += 1024) {
    int i = base + t;
    int v = (i < NN) ? deg[i] : 0;
    int x = v;
#pragma unroll
    for (int d = 1; d < 64; d <<= 1) {
      int y = __shfl_up(x, d, 64);
      if (lane >= d) x += y;
    }
    if (lane == 63) wsums[wid] = x;
    __syncthreads();
    if (wid == 0) {
      int s = (lane < 16) ? wsums[lane] : 0;
#pragma unroll
      for (int d = 1; d < 16; d <<= 1) {
        int y = __shfl_up(s, d, 64);
        if (lane >= d) s += y;
      }
      if (lane < 16) wsums[lane] = s;
    }
    __syncthreads();
    int wpre = (wid > 0) ? wsums[wid - 1] : 0;
    int excl = carry + wpre + x - v;
    if (i < NN) { offs[i] = excl; cursor[i] = excl; }
    int btot = wsums[15];
    __syncthreads();
    carry += btot;
  }
  if (t == 0) offs[NN] = carry;
}

// ---------------- CSR fill: bucket edges by dst ----------------
__global__ __launch_bounds__(256) void k_fill_csr(
    const int* __restrict__ ei, int* __restrict__ cursor, int* __restrict__ edge_src) {
  int e = blockIdx.x * blockDim.x + threadIdx.x;
  if (e < NE) {
    int d = ei[NE + e];
    int pos = atomicAdd(&cursor[d], 1);
    edge_src[pos] = ei[e];
  }
}

// ------- A_h[i] = sum_{j in Nin(i)} h_bf[j] -> Xb[:, 256:512] (bf16) --------
__global__ __launch_bounds__(256) void k_agg_h2(
    const int* __restrict__ offs, const int* __restrict__ edge_src,
    ushort_t* __restrict__ Xb) {
  int wid = threadIdx.x >> 6, lane = threadIdx.x & 63;
  int half = lane >> 5, cl = lane & 31;
  int i = blockIdx.x * 4 + wid;
  if (i >= NN) return;
  int e0 = offs[i], e1 = offs[i + 1];
  float acc[8] = {};
  int k = e0;
  for (; k + 8 <= e1; k += 8) {
    int s0 = edge_src[k + half];
    int s1 = edge_src[k + 2 + half];
    int s2 = edge_src[k + 4 + half];
    int s3 = edge_src[k + 6 + half];
    bf16x8 v0 = *(const bf16x8*)&Xb[(size_t)s0 * 512 + cl * 8];
    bf16x8 v1 = *(const bf16x8*)&Xb[(size_t)s1 * 512 + cl * 8];
    bf16x8 v2 = *(const bf16x8*)&Xb[(size_t)s2 * 512 + cl * 8];
    bf16x8 v3 = *(const bf16x8*)&Xb[(size_t)s3 * 512 + cl * 8];
#pragma unroll
    for (int j = 0; j < 8; j++) acc[j] += bf2f((unsigned short)v0[j]);
#pragma unroll
    for (int j = 0; j < 8; j++) acc[j] += bf2f((unsigned short)v1[j]);
#pragma unroll
    for (int j = 0; j < 8; j++) acc[j] += bf2f((unsigned short)v2[j]);
#pragma unroll
    for (int j = 0; j < 8; j++) acc[j] += bf2f((unsigned short)v3[j]);
  }
  for (; k + 2 <= e1; k += 2) {
    int s0 = edge_src[k + half];
    bf16x8 v0 = *(const bf16x8*)&Xb[(size_t)s0 * 512 + cl * 8];
#pragma unroll
    for (int j = 0; j < 8; j++) acc[j] += bf2f((unsigned short)v0[j]);
  }
  if (k < e1 && half == 0) {
    int s0 = edge_src[k];
    bf16x8 v0 = *(const bf16x8*)&Xb[(size_t)s0 * 512 + cl * 8];
#pragma unroll
    for (int j = 0; j < 8; j++) acc[j] += bf2f((unsigned short)v0[j]);
  }
#pragma unroll
  for (int j = 0; j < 8; j++) acc[j] += __shfl_xor(acc[j], 32, 64);
  if (half == 0) {
    bf16x8 o;
#pragma unroll
    for (int j = 0; j < 8; j++) o[j] = (short)f2bf(acc[j]);
    *(bf16x8*)(&Xb[(size_t)i * 512 + 256 + cl * 8]) = o;
  }
}

// ------ Wt[e][n][k] bf16, k in [0,512): k<256 from Ws[e][k][n], else Wn ------
__global__ __launch_bounds__(256) void k_prep_w(
    const float* __restrict__ Ws0, const float* __restrict__ Wn0,
    const float* __restrict__ Ws1, const float* __restrict__ Wn1,
    ushort_t* __restrict__ Wt1, ushort_t* __restrict__ Wt2) {
  __shared__ float tile[32][33];
  int z = blockIdx.z;
  int e = z & 7;
  const float* Ws = (z < 8) ? Ws0 : Ws1;
  const float* Wn = (z < 8) ? Wn0 : Wn1;
  ushort_t* Wt = (z < 8) ? Wt1 : Wt2;
  int kt = blockIdx.x;
  int nt = blockIdx.y;
  int tx = threadIdx.x & 31, ty = threadIdx.x >> 5;
  const float* src = (kt < 8) ? (Ws + e * 65536 + (kt * 32) * 256)
                              : (Wn + e * 65536 + ((kt - 8) * 32) * 256);
#pragma unroll
  for (int rr = 0; rr < 32; rr += 8) {
    int k = rr + ty;
    tile[k][tx] = src[k * 256 + nt * 32 + tx];
  }
  __syncthreads();
#pragma unroll
  for (int rr = 0; rr < 32; rr += 8) {
    int n = rr + ty;
    Wt[(size_t)e * 131072 + (nt * 32 + n) * 512 + kt * 32 + tx] = f2bf(tile[tx][n]);
  }
}

// ------ router weight fp16: Wr1h[n][k] = fp16(Wr1[k][n]), 256x256 -----------
__global__ __launch_bounds__(256) void k_prep_wr1h(
    const float* __restrict__ Wr1, _Float16* __restrict__ Wr1h) {
  int k = blockIdx.x;       // 0..255
  int n = threadIdx.x;      // 0..255
  Wr1h[(size_t)n * 256 + k] = (_Float16)Wr1[k * 256 + n];
}

// ------ router GEMM, single fp16 pass (K=256, 8 kt), fused logits ----------
// fp16 mantissa (10b) -> logit err ~1.5e-5; TAU=2.5e-4 (>=17 sigma) routes all
// potentially-flippable nodes to the fp32 fixup. Main-path numerics untouched.
#define TIE_TAU 2.5e-4f
__global__ __launch_bounds__(256) void k_router_mfma(
    const _Float16* __restrict__ Xh16,  // [NN][256] fp16
    const _Float16* __restrict__ Wr1h,  // [256][256] fp16 (n-major)
    const float* __restrict__ Wr1, const float* __restrict__ br1,
    const float* __restrict__ Wr2, const float* __restrict__ sf0,
    const float* __restrict__ sf1, float* __restrict__ Lpart) {
  __shared__ ushort_t As[4096];
  __shared__ ushort_t Bs[4096];
  __shared__ float Lsm[128][NEXP];
  int t = threadIdx.x;
  int w = t >> 6, lane = t & 63;
  int m0 = blockIdx.x * 128;
  int n0 = blockIdx.y * 128;
  int wm = w >> 1, wn = w & 1;
  int q16 = lane >> 4, c15 = lane & 15;
  for (int z = t; z < 128 * NEXP; z += 256) ((float*)Lsm)[z] = 0.f;

  f32x4 acc[4][4] = {};
  for (int kt = 0; kt < 8; kt++) {
    int k0 = kt * 32;
#pragma unroll
    for (int i = 0; i < 2; i++) {
      int c = w * 128 + i * 64 + lane;
      int r = c >> 2, kc = c & 3;
      int gr = m0 + r; if (gr >= NN) gr = NN - 1;
      int dst = (w * 128 + i * 64) * 8;
      gld16(Xh16 + (size_t)gr * 256 + k0 + kc * 8, (void*)&As[dst]);
      gld16(Wr1h + (size_t)(n0 + r) * 256 + k0 + kc * 8, (void*)&Bs[dst]);
    }
    __syncthreads();
    f16x8 a[4], b[4];
#pragma unroll
    for (int i = 0; i < 4; i++) {
      int ra = wm * 64 + i * 16 + c15;
      a[i] = *(const f16x8*)&As[ra * 32 + q16 * 8];
      int nb = wn * 64 + i * 16 + c15;
      b[i] = *(const f16x8*)&Bs[nb * 32 + q16 * 8];
    }
#pragma unroll
    for (int i = 0; i < 4; i++)
#pragma unroll
      for (int j = 0; j < 4; j++)
        acc[i][j] = __builtin_amdgcn_mfma_f32_16x16x32_f16(a[i], b[j], acc[i][j], 0, 0, 0);
    __syncthreads();
  }

  // epilogue: R = relu(acc + br1 + sf·w67) in regs, partial logits -> Lsm
  float bb[4], w6[4], w7[4];
#pragma unroll
  for (int j = 0; j < 4; j++) {
    int col = n0 + wn * 64 + j * 16 + c15;
    bb[j] = br1[col];
    w6[j] = Wr1[65536 + col];
    w7[j] = Wr1[65792 + col];
  }
#pragma unroll
  for (int i = 0; i < 4; i++)
#pragma unroll
    for (int v = 0; v < 4; v++) {
      int row = m0 + wm * 64 + i * 16 + q16 * 4 + v;
      float s0v = (row < NN) ? sf0[row] : 0.f;
      float s1v = (row < NN) ? sf1[row] : 0.f;
#pragma unroll
      for (int j = 0; j < 4; j++)
        acc[i][j][v] = fmaxf(acc[i][j][v] + bb[j] + s0v * w6[j] + s1v * w7[j], 0.f);
    }
#pragma unroll
  for (int e = 0; e < NEXP; e++) {
    float wr2j[4];
#pragma unroll
    for (int j = 0; j < 4; j++)
      wr2j[j] = Wr2[(n0 + wn * 64 + j * 16 + c15) * 8 + e];
    float pe[4][4];
#pragma unroll
    for (int i = 0; i < 4; i++)
#pragma unroll
      for (int v = 0; v < 4; v++) {
        float s = acc[i][0][v] * wr2j[0];
        s = fmaf(acc[i][1][v], wr2j[1], s);
        s = fmaf(acc[i][2][v], wr2j[2], s);
        s = fmaf(acc[i][3][v], wr2j[3], s);
        pe[i][v] = s;
      }
#pragma unroll
    for (int d = 1; d < 16; d <<= 1)
#pragma unroll
      for (int i = 0; i < 4; i++)
#pragma unroll
        for (int v = 0; v < 4; v++)
          pe[i][v] += __shfl_xor(pe[i][v], d, 64);
    if (c15 == 0) {
#pragma unroll
      for (int i = 0; i < 4; i++)
#pragma unroll
        for (int v = 0; v < 4; v++)
          atomicAdd(&Lsm[wm * 64 + i * 16 + q16 * 4 + v][e], pe[i][v]);
    }
  }
  __syncthreads();
  for (int z = t; z < 128 * NEXP; z += 256) {
    int lr = z >> 3, e = z & 7;
    int row = m0 + lr;
    if (row < NN)
      Lpart[(size_t)blockIdx.y * (NN * 8) + (size_t)row * 8 + e] = Lsm[lr][e];
  }
}

// ------ argmax over fused partial logits; near-ties queued for fixup --------
__global__ __launch_bounds__(256) void k_argmax(
    const float* __restrict__ Lpart, const float* __restrict__ br2,
    int* __restrict__ idx, int* __restrict__ nfix, int* __restrict__ fixlist) {
  int i = blockIdx.x * 256 + threadIdx.x;
  if (i >= NN) return;
  float best = -1e30f, second = -1e30f; int bi = 0;
#pragma unroll
  for (int e = 0; e < NEXP; e++) {
    float v = br2[e] + Lpart[(size_t)i * 8 + e]
              + Lpart[(size_t)(NN * 8) + (size_t)i * 8 + e];
    if (v > best) { second = best; best = v; bi = e; }  // strict >: first-wins
    else if (v > second) second = v;
  }
  idx[i] = bi;
  if (best - second < TIE_TAU) {
    int p = atomicAdd(nfix, 1);
    fixlist[p] = i;
  }
}

// ------ fp32 re-route for near-tie nodes (recomputes h from x) --------------
__global__ __launch_bounds__(256) void k_fixup(
    const float* __restrict__ x, const float* __restrict__ W_enc,
    const float* __restrict__ b_enc, const float* __restrict__ Wr1,
    const float* __restrict__ br1, const float* __restrict__ Wr2,
    const float* __restrict__ br2, const float* __restrict__ sf0,
    const float* __restrict__ sf1, const int* __restrict__ fixlist,
    const int* __restrict__ nfix, int* __restrict__ idx) {
  __shared__ float hsh[256];
  __shared__ float lred[4][NEXP];
  int n = *nfix;
  int t = threadIdx.x, wid = t >> 6, lane = t & 63;
  for (int qq = blockIdx.x; qq < n; qq += gridDim.x) {
    int node = fixlist[qq];
    float hv = b_enc[t];
#pragma unroll
    for (int k = 0; k < 6; k++)
      hv = fmaf(x[node * 6 + k], W_enc[k * 256 + t], hv);
    hsh[t] = fmaxf(hv, 0.f);
    __syncthreads();
    float acc = br1[t] + sf0[node] * Wr1[65536 + t] + sf1[node] * Wr1[65792 + t];
    for (int k = 0; k < 256; k++)
      acc = fmaf(hsh[k], Wr1[k * 256 + t], acc);
    float r = fmaxf(acc, 0.f);
    float le[NEXP];
#pragma unroll
    for (int e = 0; e < NEXP; e++) le[e] = r * Wr2[t * 8 + e];
#pragma unroll
    for (int d = 32; d > 0; d >>= 1)
#pragma unroll
      for (int e = 0; e < NEXP; e++) le[e] += __shfl_xor(le[e], d, 64);
    if (lane == 0) {
#pragma unroll
      for (int e = 0; e < NEXP; e++) lred[wid][e] = le[e];
    }
    __syncthreads();
    if (t == 0) {
      float best = -1e30f; int bi = 0;
      for (int e = 0; e < NEXP; e++) {
        float v = lred[0][e] + lred[1][e] + lred[2][e] + lred[3][e] + br2[e];
        if (v > best) { best = v; bi = e; }
      }
      idx[node] = bi;
    }
    __syncthreads();
  }
}

// ------ expert histogram ------
__global__ __launch_bounds__(256) void k_ecnt(
    const int* __restrict__ idx, int* __restrict__ ecnt) {
  __shared__ int bins[NEXP];
  int t = threadIdx.x;
  if (t < NEXP) bins[t] = 0;
  __syncthreads();
  for (int i = blockIdx.x * 256 + t; i < NN; i += gridDim.x * 256)
    atomicAdd(&bins[idx[i]], 1);
  __syncthreads();
  if (t < NEXP) atomicAdd(&ecnt[t], bins[t]);
}

// ------ source mask: mask[j] bit e set iff z_e[j] is needed ------
__global__ __launch_bounds__(256) void k_srcmask(
    const int* __restrict__ ei, const int* __restrict__ idx,
    unsigned int* __restrict__ mask) {
  int k = blockIdx.x * 256 + threadIdx.x;
  if (k < NE) {
    int s = ei[k], d = ei[NE + k];
    atomicOr(&mask[s], 1u << idx[d]);
  }
  if (k < NN) atomicOr(&mask[k], 1u << idx[k]);  // self bit
}

// ------ per-expert source-list sizes ------
__global__ __launch_bounds__(256) void k_scount(
    const unsigned int* __restrict__ mask, int* __restrict__ scnt) {
  __shared__ int bins[NEXP];
  int t = threadIdx.x;
  if (t < NEXP) bins[t] = 0;
  __syncthreads();
  for (int i = blockIdx.x * 256 + t; i < NN; i += gridDim.x * 256) {
    unsigned m = mask[i];
    while (m) { int b = __ffs(m) - 1; atomicAdd(&bins[b], 1); m &= m - 1; }
  }
  __syncthreads();
  if (t < NEXP) atomicAdd(&scnt[t], bins[t]);
}

// boff/bcur + tile starts + source-list offsets + layer1 tile table
__global__ void k_bucket_offs(const int* __restrict__ ecnt,
                              const int* __restrict__ scnt,
                              int* __restrict__ boff, int* __restrict__ bcur,
                              int* __restrict__ tstart,
                              int* __restrict__ soff, int* __restrict__ scur,
                              int* __restrict__ ltstart) {
  if (threadIdx.x == 0) {
    int s = 0, ts = 0, s2 = 0, lt = 0;
    for (int e = 0; e < NEXP; e++) {
      boff[e] = s; bcur[e] = s;
      tstart[e] = ts;
      ts += (ecnt[e] + 127) / 128;
      s += ecnt[e];
      soff[e] = s2; scur[e] = s2;
      ltstart[e] = lt;
      lt += (scnt[e] + 127) / 128;
      s2 += scnt[e];
    }
    boff[NEXP] = s;
    tstart[NEXP] = ts;
    soff[NEXP] = s2;
    ltstart[NEXP] = lt;
  }
}

// ---- block-aggregated bucket fill ----
#define BF_BLOCKS 64
__global__ __launch_bounds__(256) void k_bucket_fill2(
    const int* __restrict__ idx, int* __restrict__ bcur, int* __restrict__ nlist) {
  __shared__ int lcnt[NEXP];
  __shared__ int lbase[NEXP];
  int t = threadIdx.x;
  int chunk = (NN + BF_BLOCKS - 1) / BF_BLOCKS;
  int lo = blockIdx.x * chunk;
  int hi = lo + chunk; if (hi > NN) hi = NN;
  if (t < NEXP) lcnt[t] = 0;
  __syncthreads();
  for (int i = lo + t; i < hi; i += 256) atomicAdd(&lcnt[idx[i]], 1);
  __syncthreads();
  if (t < NEXP) lbase[t] = atomicAdd(&bcur[t], lcnt[t]);
  __syncthreads();
  if (t < NEXP) lcnt[t] = 0;
  __syncthreads();
  for (int i = lo + t; i < hi; i += 256) {
    int e = idx[i];
    int p = atomicAdd(&lcnt[e], 1);
    nlist[lbase[e] + p] = i;
  }
}

// ---- compact per-expert source lists from mask; also inverse map -----------
__global__ __launch_bounds__(256) void k_scompact(
    const unsigned int* __restrict__ mask, int* __restrict__ scur,
    int* __restrict__ slist, int* __restrict__ posmap) {
  __shared__ int lcnt[NEXP];
  __shared__ int lbase[NEXP];
  int t = threadIdx.x;
  int chunk = (NN + BF_BLOCKS - 1) / BF_BLOCKS;
  int lo = blockIdx.x * chunk;
  int hi = lo + chunk; if (hi > NN) hi = NN;
  if (t < NEXP) lcnt[t] = 0;
  __syncthreads();
  for (int i = lo + t; i < hi; i += 256) {
    unsigned m = mask[i];
    while (m) { int b = __ffs(m) - 1; atomicAdd(&lcnt[b], 1); m &= m - 1; }
  }
  __syncthreads();
  if (t < NEXP) lbase[t] = atomicAdd(&scur[t], lcnt[t]);
  __syncthreads();
  if (t < NEXP) lcnt[t] = 0;
  __syncthreads();
  for (int i = lo + t; i < hi; i += 256) {
    unsigned m = mask[i];
    while (m) {
      int b = __ffs(m) - 1;
      int p = atomicAdd(&lcnt[b], 1);
      int gp = lbase[b] + p;
      slist[gp] = i;
      posmap[(size_t)b * NN + i] = (gp < ZC_CAP) ? gp : 0;  // clamp (safety)
      m &= m - 1;
    }
  }
}

// ------- layer1 ALL experts, one dispatch; writes compact Zc ----------------
#define MAXT1 (8 * 391 + 8)
__global__ __launch_bounds__(256) void k_layer1_all(
    const ushort_t* __restrict__ Abf,  // Xb [NN][512] bf16
    const ushort_t* __restrict__ Wt,   // [8][256][512] bf16 (n-major)
    const float* __restrict__ b0, const int* __restrict__ idx,
    const int* __restrict__ slist, const int* __restrict__ soff,
    const int* __restrict__ ltstart,
    ushort_t* __restrict__ Zc, ushort_t* __restrict__ A2) {
  int tx = blockIdx.x;
  int e = -1;
#pragma unroll
  for (int q = 0; q < NEXP; q++)
    if (tx >= ltstart[q] && tx < ltstart[q + 1]) e = q;
  if (e < 0) return;
  int tile = tx - ltstart[e];
  int base = soff[e];
  int cnt = soff[e + 1] - base;
  int m0 = tile * 128;
  __shared__ ushort_t As[2][4096];
  __shared__ ushort_t Bs[2][4096];
  __shared__ int rows[128];
  __shared__ int sidx[128];
  int t = threadIdx.x;
  if (t < 128) {
    int r = (m0 + t < cnt) ? slist[base + m0 + t] : -1;
    rows[t] = r;
    sidx[t] = (r >= 0) ? idx[r] : -1;
  }
  __syncthreads();
  int w = t >> 6, lane = t & 63;
  int n0 = blockIdx.y * 128;
  int wm = w >> 1, wn = w & 1;
  int q16 = lane >> 4, c15 = lane & 15;
  const ushort_t* Wb = Wt + (size_t)e * 131072;

  auto STAGE = [&](int s, int kt) {
    int k0 = kt * 32;
#pragma unroll
    for (int i = 0; i < 2; i++) {
      int c = w * 128 + i * 64 + lane;
      int r = c >> 2, kc = c & 3;
      int nd = rows[r]; if (nd < 0) nd = 0;
      int dst = (w * 128 + i * 64) * 8;
      gld16(Abf + (size_t)nd * 512 + k0 + kc * 8, (void*)&As[s][dst]);
      gld16(Wb + (size_t)(n0 + r) * 512 + k0 + kc * 8, (void*)&Bs[s][dst]);
    }
  };

  f32x4 acc[4][4] = {};
  STAGE(0, 0);
  __syncthreads();
  for (int kt = 0; kt < 16; kt++) {
    int cur = kt & 1;
    if (kt < 15) STAGE(cur ^ 1, kt + 1);
    bf16x8 a[4], b[4];
#pragma unroll
    for (int i = 0; i < 4; i++) {
      int ra = wm * 64 + i * 16 + c15;
      a[i] = *(const bf16x8*)&As[cur][ra * 32 + q16 * 8];
      int nb = wn * 64 + i * 16 + c15;
      b[i] = *(const bf16x8*)&Bs[cur][nb * 32 + q16 * 8];
    }
#pragma unroll
    for (int i = 0; i < 4; i++)
#pragma unroll
      for (int j = 0; j < 4; j++)
        acc[i][j] = __builtin_amdgcn_mfma_f32_16x16x32_bf16(a[i], b[j], acc[i][j], 0, 0, 0);
    __syncthreads();
  }
#pragma unroll
  for (int i = 0; i < 4; i++) {
#pragma unroll
    for (int j = 0; j < 4; j++) {
      int col = n0 + wn * 64 + j * 16 + c15;
      float bias = b0[e * 256 + col];
#pragma unroll
      for (int v = 0; v < 4; v++) {
        int lrow = wm * 64 + i * 16 + q16 * 4 + v;
        int node = rows[lrow];
        if (node >= 0) {
          unsigned short zb = f2bf(fmaxf(acc[i][j][v] + bias, 0.f));
          int sp = base + m0 + lrow;
          if (sp < ZC_CAP) Zc[(size_t)sp * 256 + col] = zb;
          if (sidx[lrow] == e) A2[(size_t)node * 512 + col] = zb;
        }
      }
    }
  }
}

// ---- agg_z ALL buckets, one persistent dispatch (posmap indirection) -------
__global__ __launch_bounds__(256) void k_agg_z_all(
    const ushort_t* __restrict__ Zc, const int* __restrict__ offs,
    const int* __restrict__ edge_src, const int* __restrict__ nlist,
    const int* __restrict__ boff, const int* __restrict__ posmap,
    ushort_t* __restrict__ A2) {
  int wid = threadIdx.x >> 6, lane = threadIdx.x & 63;
  int half = lane >> 5, cl = lane & 31;
  for (int b = blockIdx.x * 4 + wid; b < NN; b += gridDim.x * 4) {
    int e = 0;
#pragma unroll
    for (int q = 1; q < NEXP; q++)
      if (b >= boff[q]) e = q;
    int i = nlist[b];
    const int* pm = posmap + (size_t)e * NN;
    int e0 = offs[i], e1 = offs[i + 1];
    float acc[8] = {};
    int k = e0;
    for (; k + 8 <= e1; k += 8) {
      int s0 = edge_src[k + half];
      int s1 = edge_src[k + 2 + half];
      int s2 = edge_src[k + 4 + half];
      int s3 = edge_src[k + 6 + half];
      int p0 = pm[s0], p1 = pm[s1], p2 = pm[s2], p3 = pm[s3];
      bf16x8 v0 = *(const bf16x8*)&Zc[(size_t)p0 * 256 + cl * 8];
      bf16x8 v1 = *(const bf16x8*)&Zc[(size_t)p1 * 256 + cl * 8];
      bf16x8 v2 = *(const bf16x8*)&Zc[(size_t)p2 * 256 + cl * 8];
      bf16x8 v3 = *(const bf16x8*)&Zc[(size_t)p3 * 256 + cl * 8];
#pragma unroll
      for (int j = 0; j < 8; j++) acc[j] += bf2f((unsigned short)v0[j]);
#pragma unroll
      for (int j = 0; j < 8; j++) acc[j] += bf2f((unsigned short)v1[j]);
#pragma unroll
      for (int j = 0; j < 8; j++) acc[j] += bf2f((unsigned short)v2[j]);
#pragma unroll
      for (int j = 0; j < 8; j++) acc[j] += bf2f((unsigned short)v3[j]);
    }
    for (; k + 2 <= e1; k += 2) {
      int s0 = edge_src[k + half];
      int p0 = pm[s0];
      bf16x8 v0 = *(const bf16x8*)&Zc[(size_t)p0 * 256 + cl * 8];
#pragma unroll
      for (int j = 0; j < 8; j++) acc[j] += bf2f((unsigned short)v0[j]);
    }
    if (k < e1 && half == 0) {
      int s0 = edge_src[k];
      int p0 = pm[s0];
      bf16x8 v0 = *(const bf16x8*)&Zc[(size_t)p0 * 256 + cl * 8];
#pragma unroll
      for (int j = 0; j < 8; j++) acc[j] += bf2f((unsigned short)v0[j]);
    }
#pragma unroll
    for (int j = 0; j < 8; j++) acc[j] += __shfl_xor(acc[j], 32, 64);
    if (half == 0) {
      bf16x8 o;
#pragma unroll
      for (int j = 0; j < 8; j++) o[j] = (short)f2bf(acc[j]);
      *(bf16x8*)(&A2[(size_t)i * 512 + 256 + cl * 8]) = o;
    }
  }
}

// ------- fused layer2 MFMA over all buckets -------------------
#define MAXT2 (391 + NEXP)
__global__ __launch_bounds__(256) void k_layer2_mfma(
    const ushort_t* __restrict__ A2,   // [NN][512] bf16
    const ushort_t* __restrict__ Wt,   // [8][256][512] bf16 (n-major)
    const float* __restrict__ b1, const int* __restrict__ nlist,
    const int* __restrict__ boff, const int* __restrict__ tstart,
    float* __restrict__ outp) {
  __shared__ ushort_t As[2][4096];
  __shared__ ushort_t Bs[2][4096];
  __shared__ int rows[128];
  int t = threadIdx.x;
  int tx = blockIdx.x;
  int e = -1;
#pragma unroll
  for (int q = 0; q < NEXP; q++)
    if (tx >= tstart[q] && tx < tstart[q + 1]) e = q;
  if (e < 0) return;
  int tile = tx - tstart[e];
  int base = boff[e];
  int cnt = boff[e + 1] - base;
  int m0 = tile * 128;
  if (t < 128) rows[t] = (m0 + t < cnt) ? nlist[base + m0 + t] : -1;
  __syncthreads();
  int w = t >> 6, lane = t & 63;
  int n0 = blockIdx.y * 128;
  int wm = w >> 1, wn = w & 1;
  int q16 = lane >> 4, c15 = lane & 15;
  const ushort_t* Wb = Wt + (size_t)e * 131072;

  auto STAGE = [&](int s, int kt) {
    int k0 = kt * 32;
#pragma unroll
    for (int i = 0; i < 2; i++) {
      int c = w * 128 + i * 64 + lane;
      int r = c >> 2, kc = c & 3;
      int nd = rows[r]; if (nd < 0) nd = 0;
      int dst = (w * 128 + i * 64) * 8;
      gld16(A2 + (size_t)nd * 512 + k0 + kc * 8, (void*)&As[s][dst]);
      gld16(Wb + (size_t)(n0 + r) * 512 + k0 + kc * 8, (void*)&Bs[s][dst]);
    }
  };

  f32x4 acc[4][4] = {};
  STAGE(0, 0);
  __syncthreads();
  for (int kt = 0; kt < 16; kt++) {
    int cur = kt & 1;
    if (kt < 15) STAGE(cur ^ 1, kt + 1);
    bf16x8 a[4], b[4];
#pragma unroll
    for (int i = 0; i < 4; i++) {
      int ra = wm * 64 + i * 16 + c15;
      a[i] = *(const bf16x8*)&As[cur][ra * 32 + q16 * 8];
      int nb = wn * 64 + i * 16 + c15;
      b[i] = *(const bf16x8*)&Bs[cur][nb * 32 + q16 * 8];
    }
#pragma unroll
    for (int i = 0; i < 4; i++)
#pragma unroll
      for (int j = 0; j < 4; j++)
        acc[i][j] = __builtin_amdgcn_mfma_f32_16x16x32_bf16(a[i], b[j], acc[i][j], 0, 0, 0);
    __syncthreads();
  }
#pragma unroll
  for (int i = 0; i < 4; i++) {
#pragma unroll
    for (int j = 0; j < 4; j++) {
      int col = n0 + wn * 64 + j * 16 + c15;
      float bias = b1[e * 256 + col];
#pragma unroll
      for (int v = 0; v < 4; v++) {
        int lrow = wm * 64 + i * 16 + q16 * 4 + v;
        int node = rows[lrow];
        if (node >= 0) outp[(size_t)node * 256 + col] = acc[i][j][v] + bias;
      }
    }
  }
}

static inline char* wsalloc(char*& p, size_t bytes) {
  char* r = p;
  p += (bytes + 255) & ~(size_t)255;
  return r;
}

extern "C" void kernel_launch(void* const* d_in, const int* in_sizes, int n_in,
                              void* d_out, int out_size, void* d_ws, size_t ws_size,
                              hipStream_t stream) {
  const float* x     = (const float*)d_in[0];
  const int*   ei    = (const int*)d_in[1];
  const int*   batch = (const int*)d_in[2];
  const float* W_enc = (const float*)d_in[3];
  const float* b_enc = (const float*)d_in[4];
  const float* Wr1   = (const float*)d_in[5];
  const float* br1   = (const float*)d_in[6];
  const float* Wr2   = (const float*)d_in[7];
  const float* br2   = (const float*)d_in[8];
  const float* Ws0   = (const float*)d_in[9];
  const float* Wn0   = (const float*)d_in[10];
  const float* b0    = (const float*)d_in[11];
  const float* Ws1   = (const float*)d_in[12];
  const float* Wn1   = (const float*)d_in[13];
  const float* b1    = (const float*)d_in[14];
  float* outp = (float*)d_out;

  char* p = (char*)d_ws;
  ushort_t* Xb   = (ushort_t*)wsalloc(p, (size_t)NN * 512 * 2);     // [h | A_h]
  ushort_t* Zc   = (ushort_t*)wsalloc(p, (size_t)ZC_CAP * 256 * 2); // compact z
  ushort_t* A2   = (ushort_t*)wsalloc(p, (size_t)NN * 512 * 2);     // [z_self | agg]
  _Float16* Xh16 = (_Float16*)Zc;  // alias: Xh16 dies (router) before Zc born (layer1)
  float*    Lpart= (float*)wsalloc(p, (size_t)2 * NN * 8 * 4);
  ushort_t* Wt1  = (ushort_t*)wsalloc(p, (size_t)NEXP * 256 * 512 * 2);
  ushort_t* Wt2  = (ushort_t*)wsalloc(p, (size_t)NEXP * 256 * 512 * 2);
  _Float16* Wr1h = (_Float16*)wsalloc(p, (size_t)256 * 256 * 2);
  int* edge_src  = (int*)wsalloc(p, (size_t)NE * 4);
  int* offs      = (int*)wsalloc(p, (size_t)(NN + 1) * 4);
  int* cursor    = (int*)wsalloc(p, (size_t)NN * 4);
  int* deg       = (int*)wsalloc(p, (size_t)NN * 4);
  int* idxb      = (int*)wsalloc(p, (size_t)NN * 4);
  float* sf0     = (float*)wsalloc(p, (size_t)NN * 4);
  float* sf1     = (float*)wsalloc(p, (size_t)NN * 4);
  int* nlist     = (int*)wsalloc(p, (size_t)NN * 4);
  int* fixlist   = (int*)wsalloc(p, (size_t)NN * 4);
  unsigned int* maskb = (unsigned int*)wsalloc(p, (size_t)NN * 4);
  int* slist     = (int*)wsalloc(p, (size_t)NN * NEXP * 4);
  int* posmap    = (int*)wsalloc(p, (size_t)NN * NEXP * 4);
  int* smallb    = (int*)wsalloc(p, 256 * 4);
  int* node_cnt = smallb;        // 64
  int* edge_cnt = smallb + 64;   // 64
  int* ecnt     = smallb + 128;  // 8
  int* boff     = smallb + 136;  // 9
  int* bcur     = smallb + 152;  // 8
  int* tstart   = smallb + 160;  // 9
  int* nfix     = smallb + 192;  // 1
  int* scnt     = smallb + 200;  // 8
  int* soff     = smallb + 208;  // 9
  int* scur     = smallb + 224;  // 8
  int* ltstart  = smallb + 232;  // 9

  hipMemsetAsync(deg, 0, (size_t)NN * 4, stream);
  hipMemsetAsync(smallb, 0, 256 * 4, stream);
  hipMemsetAsync(maskb, 0, (size_t)NN * 4, stream);

  k_encoder<<<NN, 256, 0, stream>>>(x, W_enc, b_enc, Xb, Xh16);
  k_count_nodes<<<64, 256, 0, stream>>>(batch, node_cnt);
  k_count_edges<<<128, 256, 0, stream>>>(ei, batch, edge_cnt, deg);
  k_sizefeat<<<(NN + 255) / 256, 256, 0, stream>>>(batch, node_cnt, edge_cnt, sf0, sf1);
  k_scan<<<1, 1024, 0, stream>>>(deg, offs, cursor);
  k_fill_csr<<<(NE + 255) / 256, 256, 0, stream>>>(ei, cursor, edge_src);
  k_agg_h2<<<(NN + 3) / 4, 256, 0, stream>>>(offs, edge_src, Xb);
  k_prep_w<<<dim3(16, 8, 16), 256, 0, stream>>>(Ws0, Wn0, Ws1, Wn1, Wt1, Wt2);
  k_prep_wr1h<<<256, 256, 0, stream>>>(Wr1, Wr1h);
  k_router_mfma<<<dim3((NN + 127) / 128, 2), 256, 0, stream>>>(
      Xh16, Wr1h, Wr1, br1, Wr2, sf0, sf1, Lpart);
  k_argmax<<<(NN + 255) / 256, 256, 0, stream>>>(Lpart, br2, idxb, nfix, fixlist);
  k_fixup<<<256, 256, 0, stream>>>(x, W_enc, b_enc, Wr1, br1, Wr2, br2,
                                   sf0, sf1, fixlist, nfix, idxb);
  k_srcmask<<<(NE + 255) / 256, 256, 0, stream>>>(ei, idxb, maskb);
  k_ecnt<<<64, 256, 0, stream>>>(idxb, ecnt);
  k_scount<<<64, 256, 0, stream>>>(maskb, scnt);
  k_bucket_offs<<<1, 64, 0, stream>>>(ecnt, scnt, boff, bcur, tstart, soff, scur, ltstart);
  k_bucket_fill2<<<BF_BLOCKS, 256, 0, stream>>>(idxb, bcur, nlist);
  k_scompact<<<BF_BLOCKS, 256, 0, stream>>>(maskb, scur, slist, posmap);
  k_layer1_all<<<dim3(MAXT1, 2), 256, 0, stream>>>(
      Xb, Wt1, b0, idxb, slist, soff, ltstart, Zc, A2);
  k_agg_z_all<<<3125, 256, 0, stream>>>(Zc, offs, edge_src, nlist, boff, posmap, A2);
  k_layer2_mfma<<<dim3(MAXT2, 2), 256, 0, stream>>>(
      A2, Wt2, b1, nlist, boff, tstart, outp);
}